// Round 18
// baseline (267.597 us; speedup 1.0000x reference)
//
#include <hip/hip_runtime.h>
#include <hip/hip_bf16.h>

typedef __hip_bfloat16 bf16_t;
typedef __attribute__((ext_vector_type(8))) short bf16x8;
typedef __attribute__((ext_vector_type(4))) float f32x4;

#define S_LEN   2048
#define D_MODEL 2048
#define N_QH    32
#define N_KVH   8
#define HEAD_D  64
#define KV_D    512
#define M_ROWS  4096
#define QK_SCALE (0.125f * 1.44269504088896340736f)   // att_scale * log2(e), folded into Q
#define NQT     16              // q-tiles of 128 rows

struct __align__(8) bf16x4s { bf16_t x, y, z, w; };

// ---------------- prep: weight transposes + RoPE table + q/k/v fp32->bf16 ----------------
__global__ void prep_kernel(const float* __restrict__ wq, const float* __restrict__ wk,
                            const float* __restrict__ wv, const float* __restrict__ wo,
                            bf16_t* __restrict__ tq, bf16_t* __restrict__ tk,
                            bf16_t* __restrict__ tv, bf16_t* __restrict__ to,
                            const float* __restrict__ query, const float* __restrict__ key_,
                            const float* __restrict__ value,
                            bf16_t* __restrict__ qbf, bf16_t* __restrict__ kbf,
                            bf16_t* __restrict__ vbf,
                            float* __restrict__ cosT, float* __restrict__ sinT) {
    const int bx = blockIdx.x, t = threadIdx.x;
    if (bx < 10240) {
        __shared__ float tile[32][33];
        const float* W; bf16_t* Wt; int N, nb, kt;
        if (bx < 4096)      { W = wq; Wt = tq; N = D_MODEL; nb = bx & 63;          kt = bx >> 6; }
        else if (bx < 5120) { int i = bx - 4096; W = wk; Wt = tk; N = KV_D; nb = i & 15; kt = i >> 4; }
        else if (bx < 6144) { int i = bx - 5120; W = wv; Wt = tv; N = KV_D; nb = i & 15; kt = i >> 4; }
        else                { int i = bx - 6144; W = wo; Wt = to; N = D_MODEL; nb = i & 63; kt = i >> 6; }
        const int K = D_MODEL;
        int n0 = nb * 32, k0 = kt * 32;
        int tx = t & 31, ty = t >> 5;   // 32 x 8
#pragma unroll
        for (int i = 0; i < 4; i++) {
            int r = ty + i * 8;
            tile[r][tx] = W[(size_t)(k0 + r) * N + n0 + tx];
        }
        __syncthreads();
#pragma unroll
        for (int i = 0; i < 4; i++) {
            int r = ty + i * 8;
            Wt[(size_t)(n0 + r) * K + k0 + tx] = __float2bfloat16(tile[tx][r]);
        }
        return;
    }
    if (bx < 10304) {
        int blk = bx - 10240;
        int j = t & 31;
        double invf = pow(10000.0, -(double)(2 * j) / 64.0);
#pragma unroll
        for (int i = 0; i < 4; i++) {
            int pos = blk * 32 + i * 8 + (t >> 5);
            double a = (double)pos * invf;
            cosT[pos * 32 + j] = (float)cos(a);
            sinT[pos * 32 + j] = (float)sin(a);
        }
        return;
    }
    const int per = M_ROWS * D_MODEL / 4;
    int tid = (bx - 10304) * 256 + t;
    for (int i = tid; i < 3 * per; i += 1536 * 256) {
        const float* src; bf16_t* dst; int off;
        if (i < per)          { src = query; dst = qbf; off = i; }
        else if (i < 2 * per) { src = key_;  dst = kbf; off = i - per; }
        else                  { src = value; dst = vbf; off = i - 2 * per; }
        float4 v = ((const float4*)src)[off];
        bf16x4s o;
        o.x = __float2bfloat16(v.x);
        o.y = __float2bfloat16(v.y);
        o.z = __float2bfloat16(v.z);
        o.w = __float2bfloat16(v.w);
        ((bf16x4s*)dst)[off] = o;
    }
}

// ---------------- async 16B global->LDS ----------------
__device__ __forceinline__ void async_copy16(const bf16_t* g, bf16_t* l) {
    __builtin_amdgcn_global_load_lds((const __attribute__((address_space(1))) void*)g,
                                     (__attribute__((address_space(3))) void*)l, 16, 0, 0);
}

// ---------------- O-projection GEMM: 128x128, BK=64, XCD-tiled ----------------
template <int ROPE, int OUTF32, int QSCALE>
__global__ __launch_bounds__(256, 2)
void gqa_gemm_kernel(const bf16_t* __restrict__ A, const bf16_t* __restrict__ Bt,
                     const float* __restrict__ bias, void* __restrict__ Cout,
                     int M, int N, int K,
                     const float* __restrict__ cosT, const float* __restrict__ sinT) {
    __shared__ __align__(16) bf16_t As[128 * 64];
    __shared__ __align__(16) bf16_t Bs[128 * 64];

    const int t = threadIdx.x;
    const int bx = blockIdx.x;
    const int xcd = bx & 7, j = bx >> 3;
    const int am0 = (((xcd >> 1) << 3) + (j >> 3)) * 128;
    const int bn0 = (((xcd & 1) << 3) + (j & 7)) * 128;

    const int l = t & 63, w = t >> 6;
    const int wr = w >> 1, wc = w & 1;
    const int lr = l & 15, lk = l >> 4;

    f32x4 acc[4][4];
#pragma unroll
    for (int i = 0; i < 4; i++)
#pragma unroll
        for (int jx = 0; jx < 4; jx++) acc[i][jx] = (f32x4)0.0f;

    const int r0 = t >> 3;
    const int c  = (t & 7) ^ (r0 & 7);
    const bf16_t* aptr = A + (size_t)(am0 + r0) * K + c * 8;
    const bf16_t* bptr = Bt + (size_t)(bn0 + r0) * K + c * 8;
    bf16_t* aLds = As + r0 * 64 + (t & 7) * 8;
    bf16_t* bLds = Bs + r0 * 64 + (t & 7) * 8;

    for (int k0 = 0; k0 < K; k0 += 64) {
#pragma unroll
        for (int s = 0; s < 4; ++s) {
            async_copy16(aptr + (size_t)(s * 32) * K + k0, aLds + s * 2048);
            async_copy16(bptr + (size_t)(s * 32) * K + k0, bLds + s * 2048);
        }
        __syncthreads();

        bf16x8 af[4][2], bfr[4][2];
#pragma unroll
        for (int mi = 0; mi < 4; mi++)
#pragma unroll
            for (int ks = 0; ks < 2; ks++)
                af[mi][ks] = *(const bf16x8*)&As[(wr * 64 + mi * 16 + lr) * 64 +
                                 ((ks * 32 + lk * 8) ^ ((lr & 7) << 3))];
#pragma unroll
        for (int ni = 0; ni < 4; ni++)
#pragma unroll
            for (int ks = 0; ks < 2; ks++)
                bfr[ni][ks] = *(const bf16x8*)&Bs[(wc * 64 + ni * 16 + lr) * 64 +
                                  ((ks * 32 + lk * 8) ^ ((lr & 7) << 3))];
#pragma unroll
        for (int mi = 0; mi < 4; mi++)
#pragma unroll
            for (int ni = 0; ni < 4; ni++)
#pragma unroll
                for (int ks = 0; ks < 2; ks++)
                    acc[mi][ni] = __builtin_amdgcn_mfma_f32_16x16x32_bf16(
                        af[mi][ks], bfr[ni][ks], acc[mi][ni], 0, 0, 0);
        __syncthreads();
    }

#pragma unroll
    for (int mi = 0; mi < 4; mi++) {
#pragma unroll
        for (int reg = 0; reg < 4; reg++) {
            int row = am0 + wr * 64 + mi * 16 + lk * 4 + reg;
            if (OUTF32) {
                float* out = (float*)Cout;
#pragma unroll
                for (int ni = 0; ni < 4; ni++) {
                    int col = bn0 + wc * 64 + ni * 16 + lr;
                    out[(size_t)row * N + col] = acc[mi][ni][reg] + bias[col];
                }
            } else if (ROPE) {
                bf16_t* out = (bf16_t*)Cout;
                int pos = row & (S_LEN - 1);
#pragma unroll
                for (int np = 0; np < 2; np++) {
                    int jj = np * 16 + lr;
                    float cs = cosT[pos * 32 + jj];
                    float sn = sinT[pos * 32 + jj];
                    int col1 = bn0 + wc * 64 + np * 16 + lr;
                    float x1 = acc[mi][np][reg] + bias[col1];
                    float x2 = acc[mi][np + 2][reg] + bias[col1 + 32];
                    float o1 = x1 * cs - x2 * sn;
                    float o2 = x2 * cs + x1 * sn;
                    if (QSCALE) { o1 *= QK_SCALE; o2 *= QK_SCALE; }
                    out[(size_t)row * N + col1]      = __float2bfloat16(o1);
                    out[(size_t)row * N + col1 + 32] = __float2bfloat16(o2);
                }
            } else {
                bf16_t* out = (bf16_t*)Cout;
#pragma unroll
                for (int ni = 0; ni < 4; ni++) {
                    int col = bn0 + wc * 64 + ni * 16 + lr;
                    out[(size_t)row * N + col] =
                        __float2bfloat16(acc[mi][ni][reg] + bias[col]);
                }
            }
        }
    }
}

// ---------------- fused Q+K+V projection GEMM: one inner loop, three epilogues ----------------
__global__ __launch_bounds__(256, 2)
void gqa_qkv_kernel(const bf16_t* __restrict__ Qbf, const bf16_t* __restrict__ Kbf,
                    const bf16_t* __restrict__ Vbf,
                    const bf16_t* __restrict__ Wtq, const bf16_t* __restrict__ Wtk,
                    const bf16_t* __restrict__ Wtv,
                    const float* __restrict__ bq, const float* __restrict__ bk,
                    const float* __restrict__ bv,
                    bf16_t* __restrict__ Qout, bf16_t* __restrict__ Kout,
                    bf16_t* __restrict__ VtOut,
                    const float* __restrict__ cosT, const float* __restrict__ sinT) {
    __shared__ __align__(16) char smem[128 * 140 * 2];   // 35840 B
    bf16_t* As = (bf16_t*)smem;                          // [128*64] loop
    bf16_t* Bs = (bf16_t*)(smem + 16384);                // [128*64] loop
    bf16_t* TT = (bf16_t*)smem;                          // [128][140] V epilogue

    const int t = threadIdx.x, bx = blockIdx.x;
    constexpr int K = D_MODEL;

    int am0, bn0, mode;
    const bf16_t *A, *Bt; const float* bias;
    if (bx < 512) {
        int xcd = bx & 7, j = bx >> 3;
        am0 = (((xcd >> 1) << 3) + (j >> 3)) * 128;
        bn0 = (((xcd & 1) << 3) + (j & 7)) * 128;
        A = Qbf; Bt = Wtq; bias = bq; mode = 0;
    } else {
        int idx = bx - 512;
        int z = idx >> 7;                  // 0:K 1:V
        int xcd = idx & 7, jj = (idx & 127) >> 3;   // 0..15
        am0 = (xcd * 4 + (jj & 3)) * 128;
        bn0 = (jj >> 2) * 128;
        A = z ? Vbf : Kbf; Bt = z ? Wtv : Wtk; bias = z ? bv : bk; mode = z ? 2 : 1;
    }

    const int l = t & 63, w = t >> 6;
    const int wr = w >> 1, wc = w & 1;
    const int lr = l & 15, lk = l >> 4;

    f32x4 acc[4][4];
#pragma unroll
    for (int i = 0; i < 4; i++)
#pragma unroll
        for (int jx = 0; jx < 4; jx++) acc[i][jx] = (f32x4)0.0f;

    const int r0 = t >> 3;
    const int c  = (t & 7) ^ (r0 & 7);
    const bf16_t* aptr = A + (size_t)(am0 + r0) * K + c * 8;
    const bf16_t* bptr = Bt + (size_t)(bn0 + r0) * K + c * 8;
    bf16_t* aLds = As + r0 * 64 + (t & 7) * 8;
    bf16_t* bLds = Bs + r0 * 64 + (t & 7) * 8;

    for (int k0 = 0; k0 < K; k0 += 64) {
#pragma unroll
        for (int s = 0; s < 4; ++s) {
            async_copy16(aptr + (size_t)(s * 32) * K + k0, aLds + s * 2048);
            async_copy16(bptr + (size_t)(s * 32) * K + k0, bLds + s * 2048);
        }
        __syncthreads();

        bf16x8 af[4][2], bfr[4][2];
#pragma unroll
        for (int mi = 0; mi < 4; mi++)
#pragma unroll
            for (int ks = 0; ks < 2; ks++)
                af[mi][ks] = *(const bf16x8*)&As[(wr * 64 + mi * 16 + lr) * 64 +
                                 ((ks * 32 + lk * 8) ^ ((lr & 7) << 3))];
#pragma unroll
        for (int ni = 0; ni < 4; ni++)
#pragma unroll
            for (int ks = 0; ks < 2; ks++)
                bfr[ni][ks] = *(const bf16x8*)&Bs[(wc * 64 + ni * 16 + lr) * 64 +
                                  ((ks * 32 + lk * 8) ^ ((lr & 7) << 3))];
#pragma unroll
        for (int mi = 0; mi < 4; mi++)
#pragma unroll
            for (int ni = 0; ni < 4; ni++)
#pragma unroll
                for (int ks = 0; ks < 2; ks++)
                    acc[mi][ni] = __builtin_amdgcn_mfma_f32_16x16x32_bf16(
                        af[mi][ks], bfr[ni][ks], acc[mi][ni], 0, 0, 0);
        __syncthreads();
    }

    if (mode == 2) {
#pragma unroll
        for (int mi = 0; mi < 4; mi++)
#pragma unroll
            for (int ni = 0; ni < 4; ni++) {
                int colL = wc * 64 + ni * 16 + lr;
                float bz = bias[bn0 + colL];
                bf16x4s pk;
                pk.x = __float2bfloat16(acc[mi][ni][0] + bz);
                pk.y = __float2bfloat16(acc[mi][ni][1] + bz);
                pk.z = __float2bfloat16(acc[mi][ni][2] + bz);
                pk.w = __float2bfloat16(acc[mi][ni][3] + bz);
                *(bf16x4s*)&TT[colL * 140 + wr * 64 + mi * 16 + lk * 4] = pk;
            }
        __syncthreads();
        const int colL = t >> 1, s0 = (t & 1) * 64;
        const int cg = bn0 + colL;
        const int bI = am0 >> 11;
        bf16_t* dst = VtOut + ((size_t)(bI * N_KVH + (cg >> 6)) * HEAD_D + (cg & 63)) * S_LEN
                      + (am0 & (S_LEN - 1)) + s0;
        const bf16_t* src = &TT[colL * 140 + s0];
#pragma unroll
        for (int i = 0; i < 8; i++)
            *(bf16x8*)(dst + i * 8) = *(const bf16x8*)(src + i * 8);
        return;
    }

    const int N = (mode == 0) ? D_MODEL : KV_D;
    bf16_t* out = (mode == 0) ? Qout : Kout;
    const float qs = (mode == 0) ? QK_SCALE : 1.0f;
#pragma unroll
    for (int mi = 0; mi < 4; mi++)
#pragma unroll
        for (int reg = 0; reg < 4; reg++) {
            int row = am0 + wr * 64 + mi * 16 + lk * 4 + reg;
            int pos = row & (S_LEN - 1);
#pragma unroll
            for (int np = 0; np < 2; np++) {
                int jj = np * 16 + lr;
                float cs = cosT[pos * 32 + jj];
                float sn = sinT[pos * 32 + jj];
                int col1 = bn0 + wc * 64 + np * 16 + lr;
                float x1 = acc[mi][np][reg] + bias[col1];
                float x2 = acc[mi][np + 2][reg] + bias[col1 + 32];
                out[(size_t)row * N + col1]      = __float2bfloat16((x1 * cs - x2 * sn) * qs);
                out[(size_t)row * N + col1 + 32] = __float2bfloat16((x2 * cs + x1 * sn) * qs);
            }
        }
}

// ---------------- K staging (512 threads: one 16B async copy per thread) ----------------
__device__ __forceinline__ void stage_K8(const bf16_t* KB, bf16_t* dst, int kt, int t) {
    const int skey = t >> 3;
    const int c    = (t & 7) ^ (skey & 7);
    async_copy16(KB + (size_t)(kt * 64 + skey) * KV_D + c * 8, dst + t * 8);
}

// ---------------- causal GQA flash attention: triple-buffered K, counted vmcnt, V from L2 ----------------
// 1024 single-q-tile blocks x 512 thr, heavy-first. Per tile: early V reg-loads
// (issued before QK, consumed at PV), K(t+2) staged async, ONE raw barrier with
// vmcnt(1) (K(t+2) stays in flight) -> no vmcnt(0) drain in the loop.
__global__ __launch_bounds__(512, 4)
void gqa_attn_kernel(const bf16_t* __restrict__ Q, const bf16_t* __restrict__ Kb,
                     const bf16_t* __restrict__ VT, bf16_t* __restrict__ Ctx) {
    __shared__ __align__(16) bf16_t Ks[3][64 * 64];    // 24 KB triple buffer
    __shared__ __align__(16) bf16_t Pw[8][16 * 72];    // 18 KB

    const int t = threadIdx.x, l = t & 63, w = t >> 6;
    const int lr = l & 15, lk = l >> 4;

    const int flat = blockIdx.x;
    const int xcd = flat & 7, j0 = flat >> 3;            // j0: 0..127
    const int qt  = NQT - 1 - (j0 >> 3);                 // heavy first
    const int rem = j0 & 7;
    const int combo = xcd * 2 + (rem >> 2);              // b*8+kvh
    const int b   = combo >> 3;
    const int kvh = combo & 7;
    const int h   = kvh * 4 + (rem & 3);

    bf16x8 vones;
#pragma unroll
    for (int i = 0; i < 8; i++) vones[i] = (short)0x3F80;

    const bf16_t* KB  = Kb + (size_t)b * S_LEN * KV_D + kvh * HEAD_D;
    const bf16_t* VTb = VT + ((size_t)(b * N_KVH + kvh) * HEAD_D) * S_LEN;

    const int q0w = qt * 128 + w * 16;
    const int qg  = q0w + lr;

    bf16x8 qf[2];
    {
        const bf16_t* qrow = Q + ((size_t)(b * S_LEN + qg)) * D_MODEL + h * HEAD_D;
        qf[0] = *(const bf16x8*)(qrow + lk * 8);
        qf[1] = *(const bf16x8*)(qrow + 32 + lk * 8);
    }

    f32x4 oaccT[4];
    f32x4 oaccS = (f32x4)0.0f;
#pragma unroll
    for (int df = 0; df < 4; df++) oaccT[df] = (f32x4)0.0f;

    const int nkt = 2 * qt + 2;

    // prologue: stage K(0), K(1); full drain once
    stage_K8(KB, Ks[0], 0, t);
    stage_K8(KB, Ks[1], 1, t);
    __syncthreads();

    for (int kt = 0; kt < nkt; ++kt) {
        const int cur = kt % 3;
        const bool compute = (kt * 64 <= q0w + 15);

        bf16x8 vfr[2][4];
        if (compute) {
            // early V loads (global, L2-resident) -- consumed at PV
#pragma unroll
            for (int ks = 0; ks < 2; ks++)
#pragma unroll
                for (int df = 0; df < 4; df++)
                    vfr[ks][df] = *(const bf16x8*)&VTb[(size_t)(df * 16 + lr) * S_LEN +
                                                       kt * 64 + ks * 32 + lk * 8];
        }
        if (kt + 2 < nkt)
            stage_K8(KB, Ks[(kt + 2) % 3], kt + 2, t);
        __builtin_amdgcn_sched_barrier(0);

        if (compute) {
            const bool diag = (kt * 64 + 63 > q0w);

            // ---- S^T = mfma(K, Q) from Ks[cur] ----
            f32x4 sfrT[4];
#pragma unroll
            for (int ni = 0; ni < 4; ni++) sfrT[ni] = (f32x4)0.0f;
            __builtin_amdgcn_s_setprio(1);
#pragma unroll
            for (int ni = 0; ni < 4; ni++)
#pragma unroll
                for (int ks = 0; ks < 2; ks++) {
                    bf16x8 kf = *(const bf16x8*)&Ks[cur][(ni * 16 + lr) * 64 +
                                    ((ks * 32 + lk * 8) ^ ((lr & 7) << 3))];
                    sfrT[ni] = __builtin_amdgcn_mfma_f32_16x16x32_bf16(kf, qf[ks],
                                                                       sfrT[ni], 0, 0, 0);
                }
            __builtin_amdgcn_s_setprio(0);

            // ---- mask + direct exp2 (fixed-shift softmax) ----
#pragma unroll
            for (int ni = 0; ni < 4; ni++) {
                float sc0 = sfrT[ni][0], sc1 = sfrT[ni][1];
                float sc2 = sfrT[ni][2], sc3 = sfrT[ni][3];
                if (diag) {
                    int kbase = kt * 64 + ni * 16 + lk * 4;
                    if (kbase + 0 > qg) sc0 = -1e30f;
                    if (kbase + 1 > qg) sc1 = -1e30f;
                    if (kbase + 2 > qg) sc2 = -1e30f;
                    if (kbase + 3 > qg) sc3 = -1e30f;
                }
                bf16x4s pk;
                pk.x = __float2bfloat16(exp2f(sc0));
                pk.y = __float2bfloat16(exp2f(sc1));
                pk.z = __float2bfloat16(exp2f(sc2));
                pk.w = __float2bfloat16(exp2f(sc3));
                *(bf16x4s*)&Pw[w][lr * 72 + ni * 16 + lk * 4] = pk;
            }

            // ---- O^T += mfma(V^T, P^T); l += mfma(ones, P^T) ----
            __builtin_amdgcn_s_setprio(1);
#pragma unroll
            for (int ks = 0; ks < 2; ks++) {
                bf16x8 pf = *(const bf16x8*)&Pw[w][lr * 72 + ks * 32 + lk * 8];
                oaccS = __builtin_amdgcn_mfma_f32_16x16x32_bf16(vones, pf, oaccS, 0, 0, 0);
#pragma unroll
                for (int df = 0; df < 4; df++)
                    oaccT[df] = __builtin_amdgcn_mfma_f32_16x16x32_bf16(vfr[ks][df], pf,
                                        oaccT[df], 0, 0, 0);
            }
            __builtin_amdgcn_s_setprio(0);
        }

        // end-of-iter: own K(kt+1) landed (vmcnt(1): only K(kt+2) may fly); raw barrier
        if (kt + 1 < nkt) {
            __builtin_amdgcn_sched_barrier(0);
            asm volatile("s_waitcnt vmcnt(1)" ::: "memory");
        }
        __builtin_amdgcn_sched_barrier(0);
        __builtin_amdgcn_s_barrier();
        __builtin_amdgcn_sched_barrier(0);
    }

    // ---- normalize + write ctx ----
    {
        float inv = 1.0f / oaccS[0];
        bf16_t* crow = Ctx + ((size_t)(b * S_LEN + qg)) * D_MODEL + h * HEAD_D;
#pragma unroll
        for (int df = 0; df < 4; df++) {
            bf16x4s ov;
            ov.x = __float2bfloat16(oaccT[df][0] * inv);
            ov.y = __float2bfloat16(oaccT[df][1] * inv);
            ov.z = __float2bfloat16(oaccT[df][2] * inv);
            ov.w = __float2bfloat16(oaccT[df][3] * inv);
            *(bf16x4s*)(crow + df * 16 + lk * 4) = ov;
        }
    }
}

extern "C" void kernel_launch(void* const* d_in, const int* in_sizes, int n_in,
                              void* d_out, int out_size, void* d_ws, size_t ws_size,
                              hipStream_t stream) {
    const float* query = (const float*)d_in[0];
    const float* key_  = (const float*)d_in[1];
    const float* value = (const float*)d_in[2];
    const float* w_q = (const float*)d_in[3];
    const float* b_q = (const float*)d_in[4];
    const float* w_k = (const float*)d_in[5];
    const float* b_k = (const float*)d_in[6];
    const float* w_v = (const float*)d_in[7];
    const float* b_v = (const float*)d_in[8];
    const float* w_o = (const float*)d_in[9];
    const float* b_o = (const float*)d_in[10];
    float* out = (float*)d_out;

    char* ws = (char*)d_ws;
    bf16_t* qbf  = (bf16_t*)(ws);                       // 16MB (query bf16; reused as ctx)
    bf16_t* qb   = (bf16_t*)(ws + (size_t)(16 << 20));  // 16MB
    bf16_t* kb   = (bf16_t*)(ws + (size_t)(32 << 20));  // 4MB
    bf16_t* vt   = (bf16_t*)(ws + (size_t)(36 << 20));  // 4MB (transposed V)
    bf16_t* wtq  = (bf16_t*)(ws + (size_t)(40 << 20));  // 8MB
    bf16_t* wtk  = (bf16_t*)(ws + (size_t)(48 << 20));  // 2MB
    bf16_t* wtv  = (bf16_t*)(ws + (size_t)(50 << 20));  // 2MB
    bf16_t* wto  = (bf16_t*)(ws + (size_t)(52 << 20));  // 8MB
    float* cosT  = (float*)(ws + (size_t)(60 << 20));   // 256KB
    float* sinT  = (float*)(ws + (size_t)(60 << 20) + (256 << 10));
    bf16_t* kbf  = (bf16_t*)(ws + (size_t)(61 << 20));  // 16MB (key bf16)
    bf16_t* vbf  = (bf16_t*)(ws + (size_t)(77 << 20));  // 16MB (value bf16)

    // 1) weight transposes + RoPE table + q/k/v conversion
    prep_kernel<<<11840, 256, 0, stream>>>(w_q, w_k, w_v, w_o, wtq, wtk, wtv, wto,
                                           query, key_, value, qbf, kbf, vbf, cosT, sinT);

    // 2) fused Q+K+V projection GEMM
    gqa_qkv_kernel<<<768, 256, 0, stream>>>(qbf, kbf, vbf, wtq, wtk, wtv,
                                            b_q, b_k, b_v, qb, kb, vt, cosT, sinT);

    // 3) attention -> ctx (reuses qbf); pipelined K staging, V from L2
    gqa_attn_kernel<<<1024, 512, 0, stream>>>(qb, kb, vt, qbf);

    // 4) output projection -> fp32 d_out
    gqa_gemm_kernel<0, 1, 0><<<512, 256, 0, stream>>>(
        qbf, wto, b_o, out, M_ROWS, D_MODEL, D_MODEL, cosT, sinT);
}

// Round 19
// 207.845 us; speedup vs baseline: 1.2875x; 1.2875x over previous
//
#include <hip/hip_runtime.h>
#include <hip/hip_bf16.h>

typedef __hip_bfloat16 bf16_t;
typedef __attribute__((ext_vector_type(8))) short bf16x8;
typedef __attribute__((ext_vector_type(4))) float f32x4;

#define S_LEN   2048
#define D_MODEL 2048
#define N_QH    32
#define N_KVH   8
#define HEAD_D  64
#define KV_D    512
#define M_ROWS  4096
#define QK_SCALE (0.125f * 1.44269504088896340736f)   // att_scale * log2(e), folded into Q
#define NQT     16              // q-tiles of 128 rows

struct __align__(8) bf16x4s { bf16_t x, y, z, w; };

// ---------------- prep: weight transposes + RoPE table + q/k/v fp32->bf16 ----------------
__global__ void prep_kernel(const float* __restrict__ wq, const float* __restrict__ wk,
                            const float* __restrict__ wv, const float* __restrict__ wo,
                            bf16_t* __restrict__ tq, bf16_t* __restrict__ tk,
                            bf16_t* __restrict__ tv, bf16_t* __restrict__ to,
                            const float* __restrict__ query, const float* __restrict__ key_,
                            const float* __restrict__ value,
                            bf16_t* __restrict__ qbf, bf16_t* __restrict__ kbf,
                            bf16_t* __restrict__ vbf,
                            float* __restrict__ cosT, float* __restrict__ sinT) {
    const int bx = blockIdx.x, t = threadIdx.x;
    if (bx < 10240) {
        __shared__ float tile[32][33];
        const float* W; bf16_t* Wt; int N, nb, kt;
        if (bx < 4096)      { W = wq; Wt = tq; N = D_MODEL; nb = bx & 63;          kt = bx >> 6; }
        else if (bx < 5120) { int i = bx - 4096; W = wk; Wt = tk; N = KV_D; nb = i & 15; kt = i >> 4; }
        else if (bx < 6144) { int i = bx - 5120; W = wv; Wt = tv; N = KV_D; nb = i & 15; kt = i >> 4; }
        else                { int i = bx - 6144; W = wo; Wt = to; N = D_MODEL; nb = i & 63; kt = i >> 6; }
        const int K = D_MODEL;
        int n0 = nb * 32, k0 = kt * 32;
        int tx = t & 31, ty = t >> 5;   // 32 x 8
#pragma unroll
        for (int i = 0; i < 4; i++) {
            int r = ty + i * 8;
            tile[r][tx] = W[(size_t)(k0 + r) * N + n0 + tx];
        }
        __syncthreads();
#pragma unroll
        for (int i = 0; i < 4; i++) {
            int r = ty + i * 8;
            Wt[(size_t)(n0 + r) * K + k0 + tx] = __float2bfloat16(tile[tx][r]);
        }
        return;
    }
    if (bx < 10304) {
        int blk = bx - 10240;
        int j = t & 31;
        double invf = pow(10000.0, -(double)(2 * j) / 64.0);
#pragma unroll
        for (int i = 0; i < 4; i++) {
            int pos = blk * 32 + i * 8 + (t >> 5);
            double a = (double)pos * invf;
            cosT[pos * 32 + j] = (float)cos(a);
            sinT[pos * 32 + j] = (float)sin(a);
        }
        return;
    }
    const int per = M_ROWS * D_MODEL / 4;
    int tid = (bx - 10304) * 256 + t;
    for (int i = tid; i < 3 * per; i += 1536 * 256) {
        const float* src; bf16_t* dst; int off;
        if (i < per)          { src = query; dst = qbf; off = i; }
        else if (i < 2 * per) { src = key_;  dst = kbf; off = i - per; }
        else                  { src = value; dst = vbf; off = i - 2 * per; }
        float4 v = ((const float4*)src)[off];
        bf16x4s o;
        o.x = __float2bfloat16(v.x);
        o.y = __float2bfloat16(v.y);
        o.z = __float2bfloat16(v.z);
        o.w = __float2bfloat16(v.w);
        ((bf16x4s*)dst)[off] = o;
    }
}

// ---------------- async 16B global->LDS ----------------
__device__ __forceinline__ void async_copy16(const bf16_t* g, bf16_t* l) {
    __builtin_amdgcn_global_load_lds((const __attribute__((address_space(1))) void*)g,
                                     (__attribute__((address_space(3))) void*)l, 16, 0, 0);
}

// ---------------- O-projection GEMM: 128x128, BK=64, XCD-tiled ----------------
template <int ROPE, int OUTF32, int QSCALE>
__global__ __launch_bounds__(256, 2)
void gqa_gemm_kernel(const bf16_t* __restrict__ A, const bf16_t* __restrict__ Bt,
                     const float* __restrict__ bias, void* __restrict__ Cout,
                     int M, int N, int K,
                     const float* __restrict__ cosT, const float* __restrict__ sinT) {
    __shared__ __align__(16) bf16_t As[128 * 64];
    __shared__ __align__(16) bf16_t Bs[128 * 64];

    const int t = threadIdx.x;
    const int bx = blockIdx.x;
    const int xcd = bx & 7, j = bx >> 3;
    const int am0 = (((xcd >> 1) << 3) + (j >> 3)) * 128;
    const int bn0 = (((xcd & 1) << 3) + (j & 7)) * 128;

    const int l = t & 63, w = t >> 6;
    const int wr = w >> 1, wc = w & 1;
    const int lr = l & 15, lk = l >> 4;

    f32x4 acc[4][4];
#pragma unroll
    for (int i = 0; i < 4; i++)
#pragma unroll
        for (int jx = 0; jx < 4; jx++) acc[i][jx] = (f32x4)0.0f;

    const int r0 = t >> 3;
    const int c  = (t & 7) ^ (r0 & 7);
    const bf16_t* aptr = A + (size_t)(am0 + r0) * K + c * 8;
    const bf16_t* bptr = Bt + (size_t)(bn0 + r0) * K + c * 8;
    bf16_t* aLds = As + r0 * 64 + (t & 7) * 8;
    bf16_t* bLds = Bs + r0 * 64 + (t & 7) * 8;

    for (int k0 = 0; k0 < K; k0 += 64) {
#pragma unroll
        for (int s = 0; s < 4; ++s) {
            async_copy16(aptr + (size_t)(s * 32) * K + k0, aLds + s * 2048);
            async_copy16(bptr + (size_t)(s * 32) * K + k0, bLds + s * 2048);
        }
        __syncthreads();

        bf16x8 af[4][2], bfr[4][2];
#pragma unroll
        for (int mi = 0; mi < 4; mi++)
#pragma unroll
            for (int ks = 0; ks < 2; ks++)
                af[mi][ks] = *(const bf16x8*)&As[(wr * 64 + mi * 16 + lr) * 64 +
                                 ((ks * 32 + lk * 8) ^ ((lr & 7) << 3))];
#pragma unroll
        for (int ni = 0; ni < 4; ni++)
#pragma unroll
            for (int ks = 0; ks < 2; ks++)
                bfr[ni][ks] = *(const bf16x8*)&Bs[(wc * 64 + ni * 16 + lr) * 64 +
                                  ((ks * 32 + lk * 8) ^ ((lr & 7) << 3))];
#pragma unroll
        for (int mi = 0; mi < 4; mi++)
#pragma unroll
            for (int ni = 0; ni < 4; ni++)
#pragma unroll
                for (int ks = 0; ks < 2; ks++)
                    acc[mi][ni] = __builtin_amdgcn_mfma_f32_16x16x32_bf16(
                        af[mi][ks], bfr[ni][ks], acc[mi][ni], 0, 0, 0);
        __syncthreads();
    }

#pragma unroll
    for (int mi = 0; mi < 4; mi++) {
#pragma unroll
        for (int reg = 0; reg < 4; reg++) {
            int row = am0 + wr * 64 + mi * 16 + lk * 4 + reg;
            if (OUTF32) {
                float* out = (float*)Cout;
#pragma unroll
                for (int ni = 0; ni < 4; ni++) {
                    int col = bn0 + wc * 64 + ni * 16 + lr;
                    out[(size_t)row * N + col] = acc[mi][ni][reg] + bias[col];
                }
            } else if (ROPE) {
                bf16_t* out = (bf16_t*)Cout;
                int pos = row & (S_LEN - 1);
#pragma unroll
                for (int np = 0; np < 2; np++) {
                    int jj = np * 16 + lr;
                    float cs = cosT[pos * 32 + jj];
                    float sn = sinT[pos * 32 + jj];
                    int col1 = bn0 + wc * 64 + np * 16 + lr;
                    float x1 = acc[mi][np][reg] + bias[col1];
                    float x2 = acc[mi][np + 2][reg] + bias[col1 + 32];
                    float o1 = x1 * cs - x2 * sn;
                    float o2 = x2 * cs + x1 * sn;
                    if (QSCALE) { o1 *= QK_SCALE; o2 *= QK_SCALE; }
                    out[(size_t)row * N + col1]      = __float2bfloat16(o1);
                    out[(size_t)row * N + col1 + 32] = __float2bfloat16(o2);
                }
            } else {
                bf16_t* out = (bf16_t*)Cout;
#pragma unroll
                for (int ni = 0; ni < 4; ni++) {
                    int col = bn0 + wc * 64 + ni * 16 + lr;
                    out[(size_t)row * N + col] =
                        __float2bfloat16(acc[mi][ni][reg] + bias[col]);
                }
            }
        }
    }
}

// ---------------- fused Q+K+V projection GEMM: one inner loop, three epilogues ----------------
__global__ __launch_bounds__(256, 2)
void gqa_qkv_kernel(const bf16_t* __restrict__ Qbf, const bf16_t* __restrict__ Kbf,
                    const bf16_t* __restrict__ Vbf,
                    const bf16_t* __restrict__ Wtq, const bf16_t* __restrict__ Wtk,
                    const bf16_t* __restrict__ Wtv,
                    const float* __restrict__ bq, const float* __restrict__ bk,
                    const float* __restrict__ bv,
                    bf16_t* __restrict__ Qout, bf16_t* __restrict__ Kout,
                    bf16_t* __restrict__ VtOut,
                    const float* __restrict__ cosT, const float* __restrict__ sinT) {
    __shared__ __align__(16) char smem[128 * 140 * 2];   // 35840 B
    bf16_t* As = (bf16_t*)smem;                          // [128*64] loop
    bf16_t* Bs = (bf16_t*)(smem + 16384);                // [128*64] loop
    bf16_t* TT = (bf16_t*)smem;                          // [128][140] V epilogue

    const int t = threadIdx.x, bx = blockIdx.x;
    constexpr int K = D_MODEL;

    int am0, bn0, mode;
    const bf16_t *A, *Bt; const float* bias;
    if (bx < 512) {
        int xcd = bx & 7, j = bx >> 3;
        am0 = (((xcd >> 1) << 3) + (j >> 3)) * 128;
        bn0 = (((xcd & 1) << 3) + (j & 7)) * 128;
        A = Qbf; Bt = Wtq; bias = bq; mode = 0;
    } else {
        int idx = bx - 512;
        int z = idx >> 7;                  // 0:K 1:V
        int xcd = idx & 7, jj = (idx & 127) >> 3;   // 0..15
        am0 = (xcd * 4 + (jj & 3)) * 128;
        bn0 = (jj >> 2) * 128;
        A = z ? Vbf : Kbf; Bt = z ? Wtv : Wtk; bias = z ? bv : bk; mode = z ? 2 : 1;
    }

    const int l = t & 63, w = t >> 6;
    const int wr = w >> 1, wc = w & 1;
    const int lr = l & 15, lk = l >> 4;

    f32x4 acc[4][4];
#pragma unroll
    for (int i = 0; i < 4; i++)
#pragma unroll
        for (int jx = 0; jx < 4; jx++) acc[i][jx] = (f32x4)0.0f;

    const int r0 = t >> 3;
    const int c  = (t & 7) ^ (r0 & 7);
    const bf16_t* aptr = A + (size_t)(am0 + r0) * K + c * 8;
    const bf16_t* bptr = Bt + (size_t)(bn0 + r0) * K + c * 8;
    bf16_t* aLds = As + r0 * 64 + (t & 7) * 8;
    bf16_t* bLds = Bs + r0 * 64 + (t & 7) * 8;

    for (int k0 = 0; k0 < K; k0 += 64) {
#pragma unroll
        for (int s = 0; s < 4; ++s) {
            async_copy16(aptr + (size_t)(s * 32) * K + k0, aLds + s * 2048);
            async_copy16(bptr + (size_t)(s * 32) * K + k0, bLds + s * 2048);
        }
        __syncthreads();

        bf16x8 af[4][2], bfr[4][2];
#pragma unroll
        for (int mi = 0; mi < 4; mi++)
#pragma unroll
            for (int ks = 0; ks < 2; ks++)
                af[mi][ks] = *(const bf16x8*)&As[(wr * 64 + mi * 16 + lr) * 64 +
                                 ((ks * 32 + lk * 8) ^ ((lr & 7) << 3))];
#pragma unroll
        for (int ni = 0; ni < 4; ni++)
#pragma unroll
            for (int ks = 0; ks < 2; ks++)
                bfr[ni][ks] = *(const bf16x8*)&Bs[(wc * 64 + ni * 16 + lr) * 64 +
                                  ((ks * 32 + lk * 8) ^ ((lr & 7) << 3))];
#pragma unroll
        for (int mi = 0; mi < 4; mi++)
#pragma unroll
            for (int ni = 0; ni < 4; ni++)
#pragma unroll
                for (int ks = 0; ks < 2; ks++)
                    acc[mi][ni] = __builtin_amdgcn_mfma_f32_16x16x32_bf16(
                        af[mi][ks], bfr[ni][ks], acc[mi][ni], 0, 0, 0);
        __syncthreads();
    }

    if (mode == 2) {
#pragma unroll
        for (int mi = 0; mi < 4; mi++)
#pragma unroll
            for (int ni = 0; ni < 4; ni++) {
                int colL = wc * 64 + ni * 16 + lr;
                float bz = bias[bn0 + colL];
                bf16x4s pk;
                pk.x = __float2bfloat16(acc[mi][ni][0] + bz);
                pk.y = __float2bfloat16(acc[mi][ni][1] + bz);
                pk.z = __float2bfloat16(acc[mi][ni][2] + bz);
                pk.w = __float2bfloat16(acc[mi][ni][3] + bz);
                *(bf16x4s*)&TT[colL * 140 + wr * 64 + mi * 16 + lk * 4] = pk;
            }
        __syncthreads();
        const int colL = t >> 1, s0 = (t & 1) * 64;
        const int cg = bn0 + colL;
        const int bI = am0 >> 11;
        bf16_t* dst = VtOut + ((size_t)(bI * N_KVH + (cg >> 6)) * HEAD_D + (cg & 63)) * S_LEN
                      + (am0 & (S_LEN - 1)) + s0;
        const bf16_t* src = &TT[colL * 140 + s0];
#pragma unroll
        for (int i = 0; i < 8; i++)
            *(bf16x8*)(dst + i * 8) = *(const bf16x8*)(src + i * 8);
        return;
    }

    const int N = (mode == 0) ? D_MODEL : KV_D;
    bf16_t* out = (mode == 0) ? Qout : Kout;
    const float qs = (mode == 0) ? QK_SCALE : 1.0f;
#pragma unroll
    for (int mi = 0; mi < 4; mi++)
#pragma unroll
        for (int reg = 0; reg < 4; reg++) {
            int row = am0 + wr * 64 + mi * 16 + lk * 4 + reg;
            int pos = row & (S_LEN - 1);
#pragma unroll
            for (int np = 0; np < 2; np++) {
                int jj = np * 16 + lr;
                float cs = cosT[pos * 32 + jj];
                float sn = sinT[pos * 32 + jj];
                int col1 = bn0 + wc * 64 + np * 16 + lr;
                float x1 = acc[mi][np][reg] + bias[col1];
                float x2 = acc[mi][np + 2][reg] + bias[col1 + 32];
                out[(size_t)row * N + col1]      = __float2bfloat16((x1 * cs - x2 * sn) * qs);
                out[(size_t)row * N + col1 + 32] = __float2bfloat16((x2 * cs + x1 * sn) * qs);
            }
        }
}

// ---------------- staging (512 threads: one 16B async copy per thread) ----------------
__device__ __forceinline__ void stage_K8(const bf16_t* KB, bf16_t* dst, int kt, int t) {
    const int skey = t >> 3;
    const int c    = (t & 7) ^ (skey & 7);
    async_copy16(KB + (size_t)(kt * 64 + skey) * KV_D + c * 8, dst + t * 8);
}
__device__ __forceinline__ void stage_V8(const bf16_t* VTb, bf16_t* dst, int kt, int t) {
    const int sd = t >> 3;
    const int c  = (t & 7) ^ (sd & 7);
    async_copy16(VTb + (size_t)sd * S_LEN + kt * 64 + c * 8, dst + t * 8);
}

// ---------------- causal GQA flash attention: triple-buffered K+V in LDS, counted vmcnt ----------------
// 1024 single-q-tile blocks x 512 thr, heavy-first. Per tile: issue stage(kt+2)
// (2 vm ops/thread), s_waitcnt vmcnt(4) (stage(kt) landed; kt+1,kt+2 in flight),
// barrier, compute, barrier. Never vmcnt(0) inside the loop.
__global__ __launch_bounds__(512, 2)
void gqa_attn_kernel(const bf16_t* __restrict__ Q, const bf16_t* __restrict__ Kb,
                     const bf16_t* __restrict__ VT, bf16_t* __restrict__ Ctx) {
    __shared__ __align__(16) bf16_t Ks[3][64 * 64];    // 24 KB
    __shared__ __align__(16) bf16_t Vs[3][64 * 64];    // 24 KB
    __shared__ __align__(16) bf16_t Pw[8][16 * 72];    // 18 KB

    const int t = threadIdx.x, l = t & 63, w = t >> 6;
    const int lr = l & 15, lk = l >> 4;

    const int flat = blockIdx.x;
    const int xcd = flat & 7, j0 = flat >> 3;            // j0: 0..127
    const int qt  = NQT - 1 - (j0 >> 3);                 // heavy first
    const int rem = j0 & 7;
    const int combo = xcd * 2 + (rem >> 2);              // b*8+kvh
    const int b   = combo >> 3;
    const int kvh = combo & 7;
    const int h   = kvh * 4 + (rem & 3);

    bf16x8 vones;
#pragma unroll
    for (int i = 0; i < 8; i++) vones[i] = (short)0x3F80;

    const bf16_t* KB  = Kb + (size_t)b * S_LEN * KV_D + kvh * HEAD_D;
    const bf16_t* VTb = VT + ((size_t)(b * N_KVH + kvh) * HEAD_D) * S_LEN;

    const int q0w = qt * 128 + w * 16;
    const int qg  = q0w + lr;

    bf16x8 qf[2];
    {
        const bf16_t* qrow = Q + ((size_t)(b * S_LEN + qg)) * D_MODEL + h * HEAD_D;
        qf[0] = *(const bf16x8*)(qrow + lk * 8);
        qf[1] = *(const bf16x8*)(qrow + 32 + lk * 8);
    }

    f32x4 oaccT[4];
    f32x4 oaccS = (f32x4)0.0f;
#pragma unroll
    for (int df = 0; df < 4; df++) oaccT[df] = (f32x4)0.0f;

    const int nkt = 2 * qt + 2;

    // prologue: stage tiles 0 and 1 (4 vm ops outstanding)
    stage_K8(KB, Ks[0], 0, t);
    stage_V8(VTb, Vs[0], 0, t);
    stage_K8(KB, Ks[1], 1, t);
    stage_V8(VTb, Vs[1], 1, t);

    for (int kt = 0; kt < nkt; ++kt) {
        const int cur = kt % 3;
        const bool compute = (kt * 64 <= q0w + 15);

        if (kt + 2 < nkt) {
            stage_K8(KB, Ks[(kt + 2) % 3], kt + 2, t);
            stage_V8(VTb, Vs[(kt + 2) % 3], kt + 2, t);
        }
        // own stage(kt) landed; up to 4 newer ops stay in flight
        __builtin_amdgcn_sched_barrier(0);
        asm volatile("s_waitcnt vmcnt(4)" ::: "memory");
        __builtin_amdgcn_sched_barrier(0);
        __builtin_amdgcn_s_barrier();
        __builtin_amdgcn_sched_barrier(0);

        if (compute) {
            const bool diag = (kt * 64 + 63 > q0w);

            // ---- S^T = mfma(K, Q) from Ks[cur] ----
            f32x4 sfrT[4];
#pragma unroll
            for (int ni = 0; ni < 4; ni++) sfrT[ni] = (f32x4)0.0f;
            __builtin_amdgcn_s_setprio(1);
#pragma unroll
            for (int ni = 0; ni < 4; ni++)
#pragma unroll
                for (int ks = 0; ks < 2; ks++) {
                    bf16x8 kf = *(const bf16x8*)&Ks[cur][(ni * 16 + lr) * 64 +
                                    ((ks * 32 + lk * 8) ^ ((lr & 7) << 3))];
                    sfrT[ni] = __builtin_amdgcn_mfma_f32_16x16x32_bf16(kf, qf[ks],
                                                                       sfrT[ni], 0, 0, 0);
                }
            __builtin_amdgcn_s_setprio(0);

            // ---- mask + direct exp2 (fixed-shift softmax) ----
#pragma unroll
            for (int ni = 0; ni < 4; ni++) {
                float sc0 = sfrT[ni][0], sc1 = sfrT[ni][1];
                float sc2 = sfrT[ni][2], sc3 = sfrT[ni][3];
                if (diag) {
                    int kbase = kt * 64 + ni * 16 + lk * 4;
                    if (kbase + 0 > qg) sc0 = -1e30f;
                    if (kbase + 1 > qg) sc1 = -1e30f;
                    if (kbase + 2 > qg) sc2 = -1e30f;
                    if (kbase + 3 > qg) sc3 = -1e30f;
                }
                bf16x4s pk;
                pk.x = __float2bfloat16(exp2f(sc0));
                pk.y = __float2bfloat16(exp2f(sc1));
                pk.z = __float2bfloat16(exp2f(sc2));
                pk.w = __float2bfloat16(exp2f(sc3));
                *(bf16x4s*)&Pw[w][lr * 72 + ni * 16 + lk * 4] = pk;
            }

            // ---- O^T += mfma(V^T, P^T); l += mfma(ones, P^T) ----
            __builtin_amdgcn_s_setprio(1);
#pragma unroll
            for (int ks = 0; ks < 2; ks++) {
                bf16x8 pf = *(const bf16x8*)&Pw[w][lr * 72 + ks * 32 + lk * 8];
                oaccS = __builtin_amdgcn_mfma_f32_16x16x32_bf16(vones, pf, oaccS, 0, 0, 0);
#pragma unroll
                for (int df = 0; df < 4; df++) {
                    bf16x8 vf = *(const bf16x8*)&Vs[cur][(df * 16 + lr) * 64 +
                                    ((ks * 32 + lk * 8) ^ ((lr & 7) << 3))];
                    oaccT[df] = __builtin_amdgcn_mfma_f32_16x16x32_bf16(vf, pf,
                                        oaccT[df], 0, 0, 0);
                }
            }
            __builtin_amdgcn_s_setprio(0);
        }

        // all reads of buf[cur] done before iter kt+1 overwrites buf[(kt+3)%3]
        __builtin_amdgcn_sched_barrier(0);
        __builtin_amdgcn_s_barrier();
        __builtin_amdgcn_sched_barrier(0);
    }

    // ---- normalize + write ctx ----
    {
        float inv = 1.0f / oaccS[0];
        bf16_t* crow = Ctx + ((size_t)(b * S_LEN + qg)) * D_MODEL + h * HEAD_D;
#pragma unroll
        for (int df = 0; df < 4; df++) {
            bf16x4s ov;
            ov.x = __float2bfloat16(oaccT[df][0] * inv);
            ov.y = __float2bfloat16(oaccT[df][1] * inv);
            ov.z = __float2bfloat16(oaccT[df][2] * inv);
            ov.w = __float2bfloat16(oaccT[df][3] * inv);
            *(bf16x4s*)(crow + df * 16 + lk * 4) = ov;
        }
    }
}

extern "C" void kernel_launch(void* const* d_in, const int* in_sizes, int n_in,
                              void* d_out, int out_size, void* d_ws, size_t ws_size,
                              hipStream_t stream) {
    const float* query = (const float*)d_in[0];
    const float* key_  = (const float*)d_in[1];
    const float* value = (const float*)d_in[2];
    const float* w_q = (const float*)d_in[3];
    const float* b_q = (const float*)d_in[4];
    const float* w_k = (const float*)d_in[5];
    const float* b_k = (const float*)d_in[6];
    const float* w_v = (const float*)d_in[7];
    const float* b_v = (const float*)d_in[8];
    const float* w_o = (const float*)d_in[9];
    const float* b_o = (const float*)d_in[10];
    float* out = (float*)d_out;

    char* ws = (char*)d_ws;
    bf16_t* qbf  = (bf16_t*)(ws);                       // 16MB (query bf16; reused as ctx)
    bf16_t* qb   = (bf16_t*)(ws + (size_t)(16 << 20));  // 16MB
    bf16_t* kb   = (bf16_t*)(ws + (size_t)(32 << 20));  // 4MB
    bf16_t* vt   = (bf16_t*)(ws + (size_t)(36 << 20));  // 4MB (transposed V)
    bf16_t* wtq  = (bf16_t*)(ws + (size_t)(40 << 20));  // 8MB
    bf16_t* wtk  = (bf16_t*)(ws + (size_t)(48 << 20));  // 2MB
    bf16_t* wtv  = (bf16_t*)(ws + (size_t)(50 << 20));  // 2MB
    bf16_t* wto  = (bf16_t*)(ws + (size_t)(52 << 20));  // 8MB
    float* cosT  = (float*)(ws + (size_t)(60 << 20));   // 256KB
    float* sinT  = (float*)(ws + (size_t)(60 << 20) + (256 << 10));
    bf16_t* kbf  = (bf16_t*)(ws + (size_t)(61 << 20));  // 16MB (key bf16)
    bf16_t* vbf  = (bf16_t*)(ws + (size_t)(77 << 20));  // 16MB (value bf16)

    // 1) weight transposes + RoPE table + q/k/v conversion
    prep_kernel<<<11840, 256, 0, stream>>>(w_q, w_k, w_v, w_o, wtq, wtk, wtv, wto,
                                           query, key_, value, qbf, kbf, vbf, cosT, sinT);

    // 2) fused Q+K+V projection GEMM
    gqa_qkv_kernel<<<768, 256, 0, stream>>>(qbf, kbf, vbf, wtq, wtk, wtv,
                                            b_q, b_k, b_v, qb, kb, vt, cosT, sinT);

    // 3) attention -> ctx (reuses qbf); triple-buffered LDS staging, counted vmcnt
    gqa_attn_kernel<<<1024, 512, 0, stream>>>(qb, kb, vt, qbf);

    // 4) output projection -> fp32 d_out
    gqa_gemm_kernel<0, 1, 0><<<512, 256, 0, stream>>>(
        qbf, wto, b_o, out, M_ROWS, D_MODEL, D_MODEL, cosT, sinT);
}

// Round 20
// 203.026 us; speedup vs baseline: 1.3180x; 1.0237x over previous
//
#include <hip/hip_runtime.h>
#include <hip/hip_bf16.h>

typedef __hip_bfloat16 bf16_t;
typedef __attribute__((ext_vector_type(8))) short bf16x8;
typedef __attribute__((ext_vector_type(4))) float f32x4;

#define S_LEN   2048
#define D_MODEL 2048
#define N_QH    32
#define N_KVH   8
#define HEAD_D  64
#define KV_D    512
#define M_ROWS  4096
#define QK_SCALE (0.125f * 1.44269504088896340736f)   // att_scale * log2(e), folded into Q
#define NQT     16              // q-tiles of 128 rows

struct __align__(8) bf16x4s { bf16_t x, y, z, w; };

// ---------------- prep: weight transposes + RoPE table + q/k/v fp32->bf16 ----------------
__global__ void prep_kernel(const float* __restrict__ wq, const float* __restrict__ wk,
                            const float* __restrict__ wv, const float* __restrict__ wo,
                            bf16_t* __restrict__ tq, bf16_t* __restrict__ tk,
                            bf16_t* __restrict__ tv, bf16_t* __restrict__ to,
                            const float* __restrict__ query, const float* __restrict__ key_,
                            const float* __restrict__ value,
                            bf16_t* __restrict__ qbf, bf16_t* __restrict__ kbf,
                            bf16_t* __restrict__ vbf,
                            float* __restrict__ cosT, float* __restrict__ sinT) {
    const int bx = blockIdx.x, t = threadIdx.x;
    if (bx < 10240) {
        __shared__ float tile[32][33];
        const float* W; bf16_t* Wt; int N, nb, kt;
        if (bx < 4096)      { W = wq; Wt = tq; N = D_MODEL; nb = bx & 63;          kt = bx >> 6; }
        else if (bx < 5120) { int i = bx - 4096; W = wk; Wt = tk; N = KV_D; nb = i & 15; kt = i >> 4; }
        else if (bx < 6144) { int i = bx - 5120; W = wv; Wt = tv; N = KV_D; nb = i & 15; kt = i >> 4; }
        else                { int i = bx - 6144; W = wo; Wt = to; N = D_MODEL; nb = i & 63; kt = i >> 6; }
        const int K = D_MODEL;
        int n0 = nb * 32, k0 = kt * 32;
        int tx = t & 31, ty = t >> 5;   // 32 x 8
#pragma unroll
        for (int i = 0; i < 4; i++) {
            int r = ty + i * 8;
            tile[r][tx] = W[(size_t)(k0 + r) * N + n0 + tx];
        }
        __syncthreads();
#pragma unroll
        for (int i = 0; i < 4; i++) {
            int r = ty + i * 8;
            Wt[(size_t)(n0 + r) * K + k0 + tx] = __float2bfloat16(tile[tx][r]);
        }
        return;
    }
    if (bx < 10304) {
        int blk = bx - 10240;
        int j = t & 31;
        double invf = pow(10000.0, -(double)(2 * j) / 64.0);
#pragma unroll
        for (int i = 0; i < 4; i++) {
            int pos = blk * 32 + i * 8 + (t >> 5);
            double a = (double)pos * invf;
            cosT[pos * 32 + j] = (float)cos(a);
            sinT[pos * 32 + j] = (float)sin(a);
        }
        return;
    }
    const int per = M_ROWS * D_MODEL / 4;
    int tid = (bx - 10304) * 256 + t;
    for (int i = tid; i < 3 * per; i += 1536 * 256) {
        const float* src; bf16_t* dst; int off;
        if (i < per)          { src = query; dst = qbf; off = i; }
        else if (i < 2 * per) { src = key_;  dst = kbf; off = i - per; }
        else                  { src = value; dst = vbf; off = i - 2 * per; }
        float4 v = ((const float4*)src)[off];
        bf16x4s o;
        o.x = __float2bfloat16(v.x);
        o.y = __float2bfloat16(v.y);
        o.z = __float2bfloat16(v.z);
        o.w = __float2bfloat16(v.w);
        ((bf16x4s*)dst)[off] = o;
    }
}

// ---------------- async 16B global->LDS ----------------
__device__ __forceinline__ void async_copy16(const bf16_t* g, bf16_t* l) {
    __builtin_amdgcn_global_load_lds((const __attribute__((address_space(1))) void*)g,
                                     (__attribute__((address_space(3))) void*)l, 16, 0, 0);
}

// ---------------- O-projection GEMM: 128x128, BK=64, XCD-tiled ----------------
template <int ROPE, int OUTF32, int QSCALE>
__global__ __launch_bounds__(256, 2)
void gqa_gemm_kernel(const bf16_t* __restrict__ A, const bf16_t* __restrict__ Bt,
                     const float* __restrict__ bias, void* __restrict__ Cout,
                     int M, int N, int K,
                     const float* __restrict__ cosT, const float* __restrict__ sinT) {
    __shared__ __align__(16) bf16_t As[128 * 64];
    __shared__ __align__(16) bf16_t Bs[128 * 64];

    const int t = threadIdx.x;
    const int bx = blockIdx.x;
    const int xcd = bx & 7, j = bx >> 3;
    const int am0 = (((xcd >> 1) << 3) + (j >> 3)) * 128;
    const int bn0 = (((xcd & 1) << 3) + (j & 7)) * 128;

    const int l = t & 63, w = t >> 6;
    const int wr = w >> 1, wc = w & 1;
    const int lr = l & 15, lk = l >> 4;

    f32x4 acc[4][4];
#pragma unroll
    for (int i = 0; i < 4; i++)
#pragma unroll
        for (int jx = 0; jx < 4; jx++) acc[i][jx] = (f32x4)0.0f;

    const int r0 = t >> 3;
    const int c  = (t & 7) ^ (r0 & 7);
    const bf16_t* aptr = A + (size_t)(am0 + r0) * K + c * 8;
    const bf16_t* bptr = Bt + (size_t)(bn0 + r0) * K + c * 8;
    bf16_t* aLds = As + r0 * 64 + (t & 7) * 8;
    bf16_t* bLds = Bs + r0 * 64 + (t & 7) * 8;

    for (int k0 = 0; k0 < K; k0 += 64) {
#pragma unroll
        for (int s = 0; s < 4; ++s) {
            async_copy16(aptr + (size_t)(s * 32) * K + k0, aLds + s * 2048);
            async_copy16(bptr + (size_t)(s * 32) * K + k0, bLds + s * 2048);
        }
        __syncthreads();

        bf16x8 af[4][2], bfr[4][2];
#pragma unroll
        for (int mi = 0; mi < 4; mi++)
#pragma unroll
            for (int ks = 0; ks < 2; ks++)
                af[mi][ks] = *(const bf16x8*)&As[(wr * 64 + mi * 16 + lr) * 64 +
                                 ((ks * 32 + lk * 8) ^ ((lr & 7) << 3))];
#pragma unroll
        for (int ni = 0; ni < 4; ni++)
#pragma unroll
            for (int ks = 0; ks < 2; ks++)
                bfr[ni][ks] = *(const bf16x8*)&Bs[(wc * 64 + ni * 16 + lr) * 64 +
                                  ((ks * 32 + lk * 8) ^ ((lr & 7) << 3))];
#pragma unroll
        for (int mi = 0; mi < 4; mi++)
#pragma unroll
            for (int ni = 0; ni < 4; ni++)
#pragma unroll
                for (int ks = 0; ks < 2; ks++)
                    acc[mi][ni] = __builtin_amdgcn_mfma_f32_16x16x32_bf16(
                        af[mi][ks], bfr[ni][ks], acc[mi][ni], 0, 0, 0);
        __syncthreads();
    }

#pragma unroll
    for (int mi = 0; mi < 4; mi++) {
#pragma unroll
        for (int reg = 0; reg < 4; reg++) {
            int row = am0 + wr * 64 + mi * 16 + lk * 4 + reg;
            if (OUTF32) {
                float* out = (float*)Cout;
#pragma unroll
                for (int ni = 0; ni < 4; ni++) {
                    int col = bn0 + wc * 64 + ni * 16 + lr;
                    out[(size_t)row * N + col] = acc[mi][ni][reg] + bias[col];
                }
            } else if (ROPE) {
                bf16_t* out = (bf16_t*)Cout;
                int pos = row & (S_LEN - 1);
#pragma unroll
                for (int np = 0; np < 2; np++) {
                    int jj = np * 16 + lr;
                    float cs = cosT[pos * 32 + jj];
                    float sn = sinT[pos * 32 + jj];
                    int col1 = bn0 + wc * 64 + np * 16 + lr;
                    float x1 = acc[mi][np][reg] + bias[col1];
                    float x2 = acc[mi][np + 2][reg] + bias[col1 + 32];
                    float o1 = x1 * cs - x2 * sn;
                    float o2 = x2 * cs + x1 * sn;
                    if (QSCALE) { o1 *= QK_SCALE; o2 *= QK_SCALE; }
                    out[(size_t)row * N + col1]      = __float2bfloat16(o1);
                    out[(size_t)row * N + col1 + 32] = __float2bfloat16(o2);
                }
            } else {
                bf16_t* out = (bf16_t*)Cout;
#pragma unroll
                for (int ni = 0; ni < 4; ni++) {
                    int col = bn0 + wc * 64 + ni * 16 + lr;
                    out[(size_t)row * N + col] =
                        __float2bfloat16(acc[mi][ni][reg] + bias[col]);
                }
            }
        }
    }
}

// ---------------- fused Q+K+V projection GEMM: one inner loop, three epilogues ----------------
__global__ __launch_bounds__(256, 2)
void gqa_qkv_kernel(const bf16_t* __restrict__ Qbf, const bf16_t* __restrict__ Kbf,
                    const bf16_t* __restrict__ Vbf,
                    const bf16_t* __restrict__ Wtq, const bf16_t* __restrict__ Wtk,
                    const bf16_t* __restrict__ Wtv,
                    const float* __restrict__ bq, const float* __restrict__ bk,
                    const float* __restrict__ bv,
                    bf16_t* __restrict__ Qout, bf16_t* __restrict__ Kout,
                    bf16_t* __restrict__ VtOut,
                    const float* __restrict__ cosT, const float* __restrict__ sinT) {
    __shared__ __align__(16) char smem[128 * 140 * 2];   // 35840 B
    bf16_t* As = (bf16_t*)smem;                          // [128*64] loop
    bf16_t* Bs = (bf16_t*)(smem + 16384);                // [128*64] loop
    bf16_t* TT = (bf16_t*)smem;                          // [128][140] V epilogue

    const int t = threadIdx.x, bx = blockIdx.x;
    constexpr int K = D_MODEL;

    int am0, bn0, mode;
    const bf16_t *A, *Bt; const float* bias;
    if (bx < 512) {
        int xcd = bx & 7, j = bx >> 3;
        am0 = (((xcd >> 1) << 3) + (j >> 3)) * 128;
        bn0 = (((xcd & 1) << 3) + (j & 7)) * 128;
        A = Qbf; Bt = Wtq; bias = bq; mode = 0;
    } else {
        int idx = bx - 512;
        int z = idx >> 7;                  // 0:K 1:V
        int xcd = idx & 7, jj = (idx & 127) >> 3;   // 0..15
        am0 = (xcd * 4 + (jj & 3)) * 128;
        bn0 = (jj >> 2) * 128;
        A = z ? Vbf : Kbf; Bt = z ? Wtv : Wtk; bias = z ? bv : bk; mode = z ? 2 : 1;
    }

    const int l = t & 63, w = t >> 6;
    const int wr = w >> 1, wc = w & 1;
    const int lr = l & 15, lk = l >> 4;

    f32x4 acc[4][4];
#pragma unroll
    for (int i = 0; i < 4; i++)
#pragma unroll
        for (int jx = 0; jx < 4; jx++) acc[i][jx] = (f32x4)0.0f;

    const int r0 = t >> 3;
    const int c  = (t & 7) ^ (r0 & 7);
    const bf16_t* aptr = A + (size_t)(am0 + r0) * K + c * 8;
    const bf16_t* bptr = Bt + (size_t)(bn0 + r0) * K + c * 8;
    bf16_t* aLds = As + r0 * 64 + (t & 7) * 8;
    bf16_t* bLds = Bs + r0 * 64 + (t & 7) * 8;

    for (int k0 = 0; k0 < K; k0 += 64) {
#pragma unroll
        for (int s = 0; s < 4; ++s) {
            async_copy16(aptr + (size_t)(s * 32) * K + k0, aLds + s * 2048);
            async_copy16(bptr + (size_t)(s * 32) * K + k0, bLds + s * 2048);
        }
        __syncthreads();

        bf16x8 af[4][2], bfr[4][2];
#pragma unroll
        for (int mi = 0; mi < 4; mi++)
#pragma unroll
            for (int ks = 0; ks < 2; ks++)
                af[mi][ks] = *(const bf16x8*)&As[(wr * 64 + mi * 16 + lr) * 64 +
                                 ((ks * 32 + lk * 8) ^ ((lr & 7) << 3))];
#pragma unroll
        for (int ni = 0; ni < 4; ni++)
#pragma unroll
            for (int ks = 0; ks < 2; ks++)
                bfr[ni][ks] = *(const bf16x8*)&Bs[(wc * 64 + ni * 16 + lr) * 64 +
                                  ((ks * 32 + lk * 8) ^ ((lr & 7) << 3))];
#pragma unroll
        for (int mi = 0; mi < 4; mi++)
#pragma unroll
            for (int ni = 0; ni < 4; ni++)
#pragma unroll
                for (int ks = 0; ks < 2; ks++)
                    acc[mi][ni] = __builtin_amdgcn_mfma_f32_16x16x32_bf16(
                        af[mi][ks], bfr[ni][ks], acc[mi][ni], 0, 0, 0);
        __syncthreads();
    }

    if (mode == 2) {
#pragma unroll
        for (int mi = 0; mi < 4; mi++)
#pragma unroll
            for (int ni = 0; ni < 4; ni++) {
                int colL = wc * 64 + ni * 16 + lr;
                float bz = bias[bn0 + colL];
                bf16x4s pk;
                pk.x = __float2bfloat16(acc[mi][ni][0] + bz);
                pk.y = __float2bfloat16(acc[mi][ni][1] + bz);
                pk.z = __float2bfloat16(acc[mi][ni][2] + bz);
                pk.w = __float2bfloat16(acc[mi][ni][3] + bz);
                *(bf16x4s*)&TT[colL * 140 + wr * 64 + mi * 16 + lk * 4] = pk;
            }
        __syncthreads();
        const int colL = t >> 1, s0 = (t & 1) * 64;
        const int cg = bn0 + colL;
        const int bI = am0 >> 11;
        bf16_t* dst = VtOut + ((size_t)(bI * N_KVH + (cg >> 6)) * HEAD_D + (cg & 63)) * S_LEN
                      + (am0 & (S_LEN - 1)) + s0;
        const bf16_t* src = &TT[colL * 140 + s0];
#pragma unroll
        for (int i = 0; i < 8; i++)
            *(bf16x8*)(dst + i * 8) = *(const bf16x8*)(src + i * 8);
        return;
    }

    const int N = (mode == 0) ? D_MODEL : KV_D;
    bf16_t* out = (mode == 0) ? Qout : Kout;
    const float qs = (mode == 0) ? QK_SCALE : 1.0f;
#pragma unroll
    for (int mi = 0; mi < 4; mi++)
#pragma unroll
        for (int reg = 0; reg < 4; reg++) {
            int row = am0 + wr * 64 + mi * 16 + lk * 4 + reg;
            int pos = row & (S_LEN - 1);
#pragma unroll
            for (int np = 0; np < 2; np++) {
                int jj = np * 16 + lr;
                float cs = cosT[pos * 32 + jj];
                float sn = sinT[pos * 32 + jj];
                int col1 = bn0 + wc * 64 + np * 16 + lr;
                float x1 = acc[mi][np][reg] + bias[col1];
                float x2 = acc[mi][np + 2][reg] + bias[col1 + 32];
                out[(size_t)row * N + col1]      = __float2bfloat16((x1 * cs - x2 * sn) * qs);
                out[(size_t)row * N + col1 + 32] = __float2bfloat16((x2 * cs + x1 * sn) * qs);
            }
        }
}

// ---------------- staging (512 threads: one 16B async copy per thread) ----------------
__device__ __forceinline__ void stage_K8(const bf16_t* KB, bf16_t* dst, int kt, int t) {
    const int skey = t >> 3;
    const int c    = (t & 7) ^ (skey & 7);
    async_copy16(KB + (size_t)(kt * 64 + skey) * KV_D + c * 8, dst + t * 8);
}
__device__ __forceinline__ void stage_V8(const bf16_t* VTb, bf16_t* dst, int kt, int t) {
    const int sd = t >> 3;
    const int c  = (t & 7) ^ (sd & 7);
    async_copy16(VTb + (size_t)sd * S_LEN + kt * 64 + c * 8, dst + t * 8);
}

// ---------------- causal GQA flash attention (round-17 structure + truncate-pack P) ----------------
// 1024 single-q-tile blocks x 512 thr, heavy-first, dbuf LDS + syncthreads.
// P -> bf16 via TRUNCATION pack: (bits(e0)>>16)|(bits(e1)&0xFFFF0000) — 2 VALU/pair
// vs ~12 for RNE. Denominator uses the same truncated P (self-consistent).
__global__ __launch_bounds__(512, 4)
void gqa_attn_kernel(const bf16_t* __restrict__ Q, const bf16_t* __restrict__ Kb,
                     const bf16_t* __restrict__ VT, bf16_t* __restrict__ Ctx) {
    __shared__ __align__(16) bf16_t Ks[2][64 * 64];
    __shared__ __align__(16) bf16_t Vs[2][64 * 64];
    __shared__ __align__(16) bf16_t Pw[8][16 * 72];

    const int t = threadIdx.x, l = t & 63, w = t >> 6;
    const int lr = l & 15, lk = l >> 4;

    const int flat = blockIdx.x;
    const int xcd = flat & 7, j0 = flat >> 3;            // j0: 0..127
    const int qt  = NQT - 1 - (j0 >> 3);                 // heavy first
    const int rem = j0 & 7;
    const int combo = xcd * 2 + (rem >> 2);              // b*8+kvh
    const int b   = combo >> 3;
    const int kvh = combo & 7;
    const int h   = kvh * 4 + (rem & 3);

    bf16x8 vones;
#pragma unroll
    for (int i = 0; i < 8; i++) vones[i] = (short)0x3F80;

    const bf16_t* KB  = Kb + (size_t)b * S_LEN * KV_D + kvh * HEAD_D;
    const bf16_t* VTb = VT + ((size_t)(b * N_KVH + kvh) * HEAD_D) * S_LEN;

    const int q0w = qt * 128 + w * 16;
    const int qg  = q0w + lr;

    bf16x8 qf[2];
    {
        const bf16_t* qrow = Q + ((size_t)(b * S_LEN + qg)) * D_MODEL + h * HEAD_D;
        qf[0] = *(const bf16x8*)(qrow + lk * 8);
        qf[1] = *(const bf16x8*)(qrow + 32 + lk * 8);
    }

    f32x4 oaccT[4];
    f32x4 oaccS = (f32x4)0.0f;
#pragma unroll
    for (int df = 0; df < 4; df++) oaccT[df] = (f32x4)0.0f;

    const int nkt = 2 * qt + 2;

    stage_K8(KB, Ks[0], 0, t);
    stage_V8(VTb, Vs[0], 0, t);
    __syncthreads();

    int cur = 0;
    for (int kt = 0; kt < nkt; ++kt) {
        const bool pre = (kt + 1 < nkt);
        if (pre) {
            stage_K8(KB, Ks[cur ^ 1], kt + 1, t);
            stage_V8(VTb, Vs[cur ^ 1], kt + 1, t);
        }

        if (kt * 64 <= q0w + 15) {                  // wave-uniform causal skip
            const bool diag = (kt * 64 + 63 > q0w);

            // ---- S^T = mfma(K, Q) ----
            f32x4 sfrT[4];
#pragma unroll
            for (int ni = 0; ni < 4; ni++) sfrT[ni] = (f32x4)0.0f;
            __builtin_amdgcn_s_setprio(1);
#pragma unroll
            for (int ni = 0; ni < 4; ni++)
#pragma unroll
                for (int ks = 0; ks < 2; ks++) {
                    bf16x8 kf = *(const bf16x8*)&Ks[cur][(ni * 16 + lr) * 64 +
                                    ((ks * 32 + lk * 8) ^ ((lr & 7) << 3))];
                    sfrT[ni] = __builtin_amdgcn_mfma_f32_16x16x32_bf16(kf, qf[ks],
                                                                       sfrT[ni], 0, 0, 0);
                }
            __builtin_amdgcn_s_setprio(0);

            // ---- mask + exp2 + truncate-pack to bf16 ----
#pragma unroll
            for (int ni = 0; ni < 4; ni++) {
                float sc0 = sfrT[ni][0], sc1 = sfrT[ni][1];
                float sc2 = sfrT[ni][2], sc3 = sfrT[ni][3];
                if (diag) {
                    int kbase = kt * 64 + ni * 16 + lk * 4;
                    if (kbase + 0 > qg) sc0 = -1e30f;
                    if (kbase + 1 > qg) sc1 = -1e30f;
                    if (kbase + 2 > qg) sc2 = -1e30f;
                    if (kbase + 3 > qg) sc3 = -1e30f;
                }
                float e0 = exp2f(sc0), e1 = exp2f(sc1);
                float e2 = exp2f(sc2), e3 = exp2f(sc3);
                unsigned u0 = __builtin_bit_cast(unsigned, e0);
                unsigned u1 = __builtin_bit_cast(unsigned, e1);
                unsigned u2 = __builtin_bit_cast(unsigned, e2);
                unsigned u3 = __builtin_bit_cast(unsigned, e3);
                uint2 pk;
                pk.x = (u0 >> 16) | (u1 & 0xFFFF0000u);   // v_lshrrev + v_and_or
                pk.y = (u2 >> 16) | (u3 & 0xFFFF0000u);
                *(uint2*)&Pw[w][lr * 72 + ni * 16 + lk * 4] = pk;
            }

            // ---- O^T += mfma(V^T, P^T); l += mfma(ones, P^T) ----
            __builtin_amdgcn_s_setprio(1);
#pragma unroll
            for (int ks = 0; ks < 2; ks++) {
                bf16x8 pf = *(const bf16x8*)&Pw[w][lr * 72 + ks * 32 + lk * 8];
                oaccS = __builtin_amdgcn_mfma_f32_16x16x32_bf16(vones, pf, oaccS, 0, 0, 0);
#pragma unroll
                for (int df = 0; df < 4; df++) {
                    bf16x8 vf = *(const bf16x8*)&Vs[cur][(df * 16 + lr) * 64 +
                                    ((ks * 32 + lk * 8) ^ ((lr & 7) << 3))];
                    oaccT[df] = __builtin_amdgcn_mfma_f32_16x16x32_bf16(vf, pf,
                                        oaccT[df], 0, 0, 0);
                }
            }
            __builtin_amdgcn_s_setprio(0);
        }

        __syncthreads();
        cur ^= 1;
    }

    // ---- normalize + write ctx (RNE conversions here; once per block) ----
    {
        float inv = 1.0f / oaccS[0];
        bf16_t* crow = Ctx + ((size_t)(b * S_LEN + qg)) * D_MODEL + h * HEAD_D;
#pragma unroll
        for (int df = 0; df < 4; df++) {
            bf16x4s ov;
            ov.x = __float2bfloat16(oaccT[df][0] * inv);
            ov.y = __float2bfloat16(oaccT[df][1] * inv);
            ov.z = __float2bfloat16(oaccT[df][2] * inv);
            ov.w = __float2bfloat16(oaccT[df][3] * inv);
            *(bf16x4s*)(crow + df * 16 + lk * 4) = ov;
        }
    }
}

extern "C" void kernel_launch(void* const* d_in, const int* in_sizes, int n_in,
                              void* d_out, int out_size, void* d_ws, size_t ws_size,
                              hipStream_t stream) {
    const float* query = (const float*)d_in[0];
    const float* key_  = (const float*)d_in[1];
    const float* value = (const float*)d_in[2];
    const float* w_q = (const float*)d_in[3];
    const float* b_q = (const float*)d_in[4];
    const float* w_k = (const float*)d_in[5];
    const float* b_k = (const float*)d_in[6];
    const float* w_v = (const float*)d_in[7];
    const float* b_v = (const float*)d_in[8];
    const float* w_o = (const float*)d_in[9];
    const float* b_o = (const float*)d_in[10];
    float* out = (float*)d_out;

    char* ws = (char*)d_ws;
    bf16_t* qbf  = (bf16_t*)(ws);                       // 16MB (query bf16; reused as ctx)
    bf16_t* qb   = (bf16_t*)(ws + (size_t)(16 << 20));  // 16MB
    bf16_t* kb   = (bf16_t*)(ws + (size_t)(32 << 20));  // 4MB
    bf16_t* vt   = (bf16_t*)(ws + (size_t)(36 << 20));  // 4MB (transposed V)
    bf16_t* wtq  = (bf16_t*)(ws + (size_t)(40 << 20));  // 8MB
    bf16_t* wtk  = (bf16_t*)(ws + (size_t)(48 << 20));  // 2MB
    bf16_t* wtv  = (bf16_t*)(ws + (size_t)(50 << 20));  // 2MB
    bf16_t* wto  = (bf16_t*)(ws + (size_t)(52 << 20));  // 8MB
    float* cosT  = (float*)(ws + (size_t)(60 << 20));   // 256KB
    float* sinT  = (float*)(ws + (size_t)(60 << 20) + (256 << 10));
    bf16_t* kbf  = (bf16_t*)(ws + (size_t)(61 << 20));  // 16MB (key bf16)
    bf16_t* vbf  = (bf16_t*)(ws + (size_t)(77 << 20));  // 16MB (value bf16)

    // 1) weight transposes + RoPE table + q/k/v conversion
    prep_kernel<<<11840, 256, 0, stream>>>(w_q, w_k, w_v, w_o, wtq, wtk, wtv, wto,
                                           query, key_, value, qbf, kbf, vbf, cosT, sinT);

    // 2) fused Q+K+V projection GEMM
    gqa_qkv_kernel<<<768, 256, 0, stream>>>(qbf, kbf, vbf, wtq, wtk, wtv,
                                            b_q, b_k, b_v, qb, kb, vt, cosT, sinT);

    // 3) attention -> ctx (reuses qbf); round-17 loop + truncate-pack softmax
    gqa_attn_kernel<<<1024, 512, 0, stream>>>(qb, kb, vt, qbf);

    // 4) output projection -> fp32 d_out
    gqa_gemm_kernel<0, 1, 0><<<512, 256, 0, stream>>>(
        qbf, wto, b_o, out, M_ROWS, D_MODEL, D_MODEL, cosT, sinT);
}

// Round 21
// 201.826 us; speedup vs baseline: 1.3259x; 1.0059x over previous
//
#include <hip/hip_runtime.h>
#include <hip/hip_bf16.h>

typedef __hip_bfloat16 bf16_t;
typedef __attribute__((ext_vector_type(8))) short bf16x8;
typedef __attribute__((ext_vector_type(4))) float f32x4;
typedef __attribute__((ext_vector_type(16))) float f32x16;

#define S_LEN   2048
#define D_MODEL 2048
#define N_QH    32
#define N_KVH   8
#define HEAD_D  64
#define KV_D    512
#define M_ROWS  4096
#define QK_SCALE (0.125f * 1.44269504088896340736f)   // att_scale * log2(e), folded into Q
#define NQT     16              // q-tiles of 128 rows

struct __align__(8) bf16x4s { bf16_t x, y, z, w; };

// ---------------- prep: weight transposes + RoPE table + q/k/v fp32->bf16 ----------------
__global__ void prep_kernel(const float* __restrict__ wq, const float* __restrict__ wk,
                            const float* __restrict__ wv, const float* __restrict__ wo,
                            bf16_t* __restrict__ tq, bf16_t* __restrict__ tk,
                            bf16_t* __restrict__ tv, bf16_t* __restrict__ to,
                            const float* __restrict__ query, const float* __restrict__ key_,
                            const float* __restrict__ value,
                            bf16_t* __restrict__ qbf, bf16_t* __restrict__ kbf,
                            bf16_t* __restrict__ vbf,
                            float* __restrict__ cosT, float* __restrict__ sinT) {
    const int bx = blockIdx.x, t = threadIdx.x;
    if (bx < 10240) {
        __shared__ float tile[32][33];
        const float* W; bf16_t* Wt; int N, nb, kt;
        if (bx < 4096)      { W = wq; Wt = tq; N = D_MODEL; nb = bx & 63;          kt = bx >> 6; }
        else if (bx < 5120) { int i = bx - 4096; W = wk; Wt = tk; N = KV_D; nb = i & 15; kt = i >> 4; }
        else if (bx < 6144) { int i = bx - 5120; W = wv; Wt = tv; N = KV_D; nb = i & 15; kt = i >> 4; }
        else                { int i = bx - 6144; W = wo; Wt = to; N = D_MODEL; nb = i & 63; kt = i >> 6; }
        const int K = D_MODEL;
        int n0 = nb * 32, k0 = kt * 32;
        int tx = t & 31, ty = t >> 5;   // 32 x 8
#pragma unroll
        for (int i = 0; i < 4; i++) {
            int r = ty + i * 8;
            tile[r][tx] = W[(size_t)(k0 + r) * N + n0 + tx];
        }
        __syncthreads();
#pragma unroll
        for (int i = 0; i < 4; i++) {
            int r = ty + i * 8;
            Wt[(size_t)(n0 + r) * K + k0 + tx] = __float2bfloat16(tile[tx][r]);
        }
        return;
    }
    if (bx < 10304) {
        int blk = bx - 10240;
        int j = t & 31;
        double invf = pow(10000.0, -(double)(2 * j) / 64.0);
#pragma unroll
        for (int i = 0; i < 4; i++) {
            int pos = blk * 32 + i * 8 + (t >> 5);
            double a = (double)pos * invf;
            cosT[pos * 32 + j] = (float)cos(a);
            sinT[pos * 32 + j] = (float)sin(a);
        }
        return;
    }
    const int per = M_ROWS * D_MODEL / 4;
    int tid = (bx - 10304) * 256 + t;
    for (int i = tid; i < 3 * per; i += 1536 * 256) {
        const float* src; bf16_t* dst; int off;
        if (i < per)          { src = query; dst = qbf; off = i; }
        else if (i < 2 * per) { src = key_;  dst = kbf; off = i - per; }
        else                  { src = value; dst = vbf; off = i - 2 * per; }
        float4 v = ((const float4*)src)[off];
        bf16x4s o;
        o.x = __float2bfloat16(v.x);
        o.y = __float2bfloat16(v.y);
        o.z = __float2bfloat16(v.z);
        o.w = __float2bfloat16(v.w);
        ((bf16x4s*)dst)[off] = o;
    }
}

// ---------------- async 16B global->LDS ----------------
__device__ __forceinline__ void async_copy16(const bf16_t* g, bf16_t* l) {
    __builtin_amdgcn_global_load_lds((const __attribute__((address_space(1))) void*)g,
                                     (__attribute__((address_space(3))) void*)l, 16, 0, 0);
}

// ---------------- O-projection GEMM: 128x128, BK=64, XCD-tiled ----------------
template <int ROPE, int OUTF32, int QSCALE>
__global__ __launch_bounds__(256, 2)
void gqa_gemm_kernel(const bf16_t* __restrict__ A, const bf16_t* __restrict__ Bt,
                     const float* __restrict__ bias, void* __restrict__ Cout,
                     int M, int N, int K,
                     const float* __restrict__ cosT, const float* __restrict__ sinT) {
    __shared__ __align__(16) bf16_t As[128 * 64];
    __shared__ __align__(16) bf16_t Bs[128 * 64];

    const int t = threadIdx.x;
    const int bx = blockIdx.x;
    const int xcd = bx & 7, j = bx >> 3;
    const int am0 = (((xcd >> 1) << 3) + (j >> 3)) * 128;
    const int bn0 = (((xcd & 1) << 3) + (j & 7)) * 128;

    const int l = t & 63, w = t >> 6;
    const int wr = w >> 1, wc = w & 1;
    const int lr = l & 15, lk = l >> 4;

    f32x4 acc[4][4];
#pragma unroll
    for (int i = 0; i < 4; i++)
#pragma unroll
        for (int jx = 0; jx < 4; jx++) acc[i][jx] = (f32x4)0.0f;

    const int r0 = t >> 3;
    const int c  = (t & 7) ^ (r0 & 7);
    const bf16_t* aptr = A + (size_t)(am0 + r0) * K + c * 8;
    const bf16_t* bptr = Bt + (size_t)(bn0 + r0) * K + c * 8;
    bf16_t* aLds = As + r0 * 64 + (t & 7) * 8;
    bf16_t* bLds = Bs + r0 * 64 + (t & 7) * 8;

    for (int k0 = 0; k0 < K; k0 += 64) {
#pragma unroll
        for (int s = 0; s < 4; ++s) {
            async_copy16(aptr + (size_t)(s * 32) * K + k0, aLds + s * 2048);
            async_copy16(bptr + (size_t)(s * 32) * K + k0, bLds + s * 2048);
        }
        __syncthreads();

        bf16x8 af[4][2], bfr[4][2];
#pragma unroll
        for (int mi = 0; mi < 4; mi++)
#pragma unroll
            for (int ks = 0; ks < 2; ks++)
                af[mi][ks] = *(const bf16x8*)&As[(wr * 64 + mi * 16 + lr) * 64 +
                                 ((ks * 32 + lk * 8) ^ ((lr & 7) << 3))];
#pragma unroll
        for (int ni = 0; ni < 4; ni++)
#pragma unroll
            for (int ks = 0; ks < 2; ks++)
                bfr[ni][ks] = *(const bf16x8*)&Bs[(wc * 64 + ni * 16 + lr) * 64 +
                                  ((ks * 32 + lk * 8) ^ ((lr & 7) << 3))];
#pragma unroll
        for (int mi = 0; mi < 4; mi++)
#pragma unroll
            for (int ni = 0; ni < 4; ni++)
#pragma unroll
                for (int ks = 0; ks < 2; ks++)
                    acc[mi][ni] = __builtin_amdgcn_mfma_f32_16x16x32_bf16(
                        af[mi][ks], bfr[ni][ks], acc[mi][ni], 0, 0, 0);
        __syncthreads();
    }

#pragma unroll
    for (int mi = 0; mi < 4; mi++) {
#pragma unroll
        for (int reg = 0; reg < 4; reg++) {
            int row = am0 + wr * 64 + mi * 16 + lk * 4 + reg;
            if (OUTF32) {
                float* out = (float*)Cout;
#pragma unroll
                for (int ni = 0; ni < 4; ni++) {
                    int col = bn0 + wc * 64 + ni * 16 + lr;
                    out[(size_t)row * N + col] = acc[mi][ni][reg] + bias[col];
                }
            } else if (ROPE) {
                bf16_t* out = (bf16_t*)Cout;
                int pos = row & (S_LEN - 1);
#pragma unroll
                for (int np = 0; np < 2; np++) {
                    int jj = np * 16 + lr;
                    float cs = cosT[pos * 32 + jj];
                    float sn = sinT[pos * 32 + jj];
                    int col1 = bn0 + wc * 64 + np * 16 + lr;
                    float x1 = acc[mi][np][reg] + bias[col1];
                    float x2 = acc[mi][np + 2][reg] + bias[col1 + 32];
                    float o1 = x1 * cs - x2 * sn;
                    float o2 = x2 * cs + x1 * sn;
                    if (QSCALE) { o1 *= QK_SCALE; o2 *= QK_SCALE; }
                    out[(size_t)row * N + col1]      = __float2bfloat16(o1);
                    out[(size_t)row * N + col1 + 32] = __float2bfloat16(o2);
                }
            } else {
                bf16_t* out = (bf16_t*)Cout;
#pragma unroll
                for (int ni = 0; ni < 4; ni++) {
                    int col = bn0 + wc * 64 + ni * 16 + lr;
                    out[(size_t)row * N + col] =
                        __float2bfloat16(acc[mi][ni][reg] + bias[col]);
                }
            }
        }
    }
}

// ---------------- fused Q+K+V projection GEMM: one inner loop, three epilogues ----------------
__global__ __launch_bounds__(256, 2)
void gqa_qkv_kernel(const bf16_t* __restrict__ Qbf, const bf16_t* __restrict__ Kbf,
                    const bf16_t* __restrict__ Vbf,
                    const bf16_t* __restrict__ Wtq, const bf16_t* __restrict__ Wtk,
                    const bf16_t* __restrict__ Wtv,
                    const float* __restrict__ bq, const float* __restrict__ bk,
                    const float* __restrict__ bv,
                    bf16_t* __restrict__ Qout, bf16_t* __restrict__ Kout,
                    bf16_t* __restrict__ VtOut,
                    const float* __restrict__ cosT, const float* __restrict__ sinT) {
    __shared__ __align__(16) char smem[128 * 140 * 2];   // 35840 B
    bf16_t* As = (bf16_t*)smem;                          // [128*64] loop
    bf16_t* Bs = (bf16_t*)(smem + 16384);                // [128*64] loop
    bf16_t* TT = (bf16_t*)smem;                          // [128][140] V epilogue

    const int t = threadIdx.x, bx = blockIdx.x;
    constexpr int K = D_MODEL;

    int am0, bn0, mode;
    const bf16_t *A, *Bt; const float* bias;
    if (bx < 512) {
        int xcd = bx & 7, j = bx >> 3;
        am0 = (((xcd >> 1) << 3) + (j >> 3)) * 128;
        bn0 = (((xcd & 1) << 3) + (j & 7)) * 128;
        A = Qbf; Bt = Wtq; bias = bq; mode = 0;
    } else {
        int idx = bx - 512;
        int z = idx >> 7;                  // 0:K 1:V
        int xcd = idx & 7, jj = (idx & 127) >> 3;   // 0..15
        am0 = (xcd * 4 + (jj & 3)) * 128;
        bn0 = (jj >> 2) * 128;
        A = z ? Vbf : Kbf; Bt = z ? Wtv : Wtk; bias = z ? bv : bk; mode = z ? 2 : 1;
    }

    const int l = t & 63, w = t >> 6;
    const int wr = w >> 1, wc = w & 1;
    const int lr = l & 15, lk = l >> 4;

    f32x4 acc[4][4];
#pragma unroll
    for (int i = 0; i < 4; i++)
#pragma unroll
        for (int jx = 0; jx < 4; jx++) acc[i][jx] = (f32x4)0.0f;

    const int r0 = t >> 3;
    const int c  = (t & 7) ^ (r0 & 7);
    const bf16_t* aptr = A + (size_t)(am0 + r0) * K + c * 8;
    const bf16_t* bptr = Bt + (size_t)(bn0 + r0) * K + c * 8;
    bf16_t* aLds = As + r0 * 64 + (t & 7) * 8;
    bf16_t* bLds = Bs + r0 * 64 + (t & 7) * 8;

    for (int k0 = 0; k0 < K; k0 += 64) {
#pragma unroll
        for (int s = 0; s < 4; ++s) {
            async_copy16(aptr + (size_t)(s * 32) * K + k0, aLds + s * 2048);
            async_copy16(bptr + (size_t)(s * 32) * K + k0, bLds + s * 2048);
        }
        __syncthreads();

        bf16x8 af[4][2], bfr[4][2];
#pragma unroll
        for (int mi = 0; mi < 4; mi++)
#pragma unroll
            for (int ks = 0; ks < 2; ks++)
                af[mi][ks] = *(const bf16x8*)&As[(wr * 64 + mi * 16 + lr) * 64 +
                                 ((ks * 32 + lk * 8) ^ ((lr & 7) << 3))];
#pragma unroll
        for (int ni = 0; ni < 4; ni++)
#pragma unroll
            for (int ks = 0; ks < 2; ks++)
                bfr[ni][ks] = *(const bf16x8*)&Bs[(wc * 64 + ni * 16 + lr) * 64 +
                                  ((ks * 32 + lk * 8) ^ ((lr & 7) << 3))];
#pragma unroll
        for (int mi = 0; mi < 4; mi++)
#pragma unroll
            for (int ni = 0; ni < 4; ni++)
#pragma unroll
                for (int ks = 0; ks < 2; ks++)
                    acc[mi][ni] = __builtin_amdgcn_mfma_f32_16x16x32_bf16(
                        af[mi][ks], bfr[ni][ks], acc[mi][ni], 0, 0, 0);
        __syncthreads();
    }

    if (mode == 2) {
#pragma unroll
        for (int mi = 0; mi < 4; mi++)
#pragma unroll
            for (int ni = 0; ni < 4; ni++) {
                int colL = wc * 64 + ni * 16 + lr;
                float bz = bias[bn0 + colL];
                bf16x4s pk;
                pk.x = __float2bfloat16(acc[mi][ni][0] + bz);
                pk.y = __float2bfloat16(acc[mi][ni][1] + bz);
                pk.z = __float2bfloat16(acc[mi][ni][2] + bz);
                pk.w = __float2bfloat16(acc[mi][ni][3] + bz);
                *(bf16x4s*)&TT[colL * 140 + wr * 64 + mi * 16 + lk * 4] = pk;
            }
        __syncthreads();
        const int colL = t >> 1, s0 = (t & 1) * 64;
        const int cg = bn0 + colL;
        const int bI = am0 >> 11;
        bf16_t* dst = VtOut + ((size_t)(bI * N_KVH + (cg >> 6)) * HEAD_D + (cg & 63)) * S_LEN
                      + (am0 & (S_LEN - 1)) + s0;
        const bf16_t* src = &TT[colL * 140 + s0];
#pragma unroll
        for (int i = 0; i < 8; i++)
            *(bf16x8*)(dst + i * 8) = *(const bf16x8*)(src + i * 8);
        return;
    }

    const int N = (mode == 0) ? D_MODEL : KV_D;
    bf16_t* out = (mode == 0) ? Qout : Kout;
    const float qs = (mode == 0) ? QK_SCALE : 1.0f;
#pragma unroll
    for (int mi = 0; mi < 4; mi++)
#pragma unroll
        for (int reg = 0; reg < 4; reg++) {
            int row = am0 + wr * 64 + mi * 16 + lk * 4 + reg;
            int pos = row & (S_LEN - 1);
#pragma unroll
            for (int np = 0; np < 2; np++) {
                int jj = np * 16 + lr;
                float cs = cosT[pos * 32 + jj];
                float sn = sinT[pos * 32 + jj];
                int col1 = bn0 + wc * 64 + np * 16 + lr;
                float x1 = acc[mi][np][reg] + bias[col1];
                float x2 = acc[mi][np + 2][reg] + bias[col1 + 32];
                out[(size_t)row * N + col1]      = __float2bfloat16((x1 * cs - x2 * sn) * qs);
                out[(size_t)row * N + col1 + 32] = __float2bfloat16((x2 * cs + x1 * sn) * qs);
            }
        }
}

// ---------------- staging (256 threads: two 16B async copies per thread) ----------------
__device__ __forceinline__ void stage_K4(const bf16_t* KB, bf16_t* dst, int kt, int t) {
    const int skey = t >> 3;                // 0..31
    const int c    = (t & 7) ^ (skey & 7);  // (s*32+skey)&7 == skey&7
#pragma unroll
    for (int s = 0; s < 2; ++s)
        async_copy16(KB + (size_t)(kt * 64 + s * 32 + skey) * KV_D + c * 8,
                     dst + s * 2048 + t * 8);
}
__device__ __forceinline__ void stage_V4(const bf16_t* VTb, bf16_t* dst, int kt, int t) {
    const int sd = t >> 3;                  // 0..31
    const int c  = (t & 7) ^ (sd & 7);
#pragma unroll
    for (int s = 0; s < 2; ++s)
        async_copy16(VTb + (size_t)(s * 32 + sd) * S_LEN + kt * 64 + c * 8,
                     dst + s * 2048 + t * 8);
}

// ---------------- causal GQA flash attention: 32x32 MFMA, 4 waves x 32 q-rows ----------------
// 1024 single-q-tile blocks x 256 thr, heavy-first, dbuf LDS. 32x32x16 halves
// per-q LDS read traffic (the measured bottleneck). C/D: col=lane&31(q),
// row=(reg&3)+8*(reg>>2)+4*(lane>>5) (key/d). Denominator: in-register sum + 1 shfl.
__global__ __launch_bounds__(256, 3)
void gqa_attn_kernel(const bf16_t* __restrict__ Q, const bf16_t* __restrict__ Kb,
                     const bf16_t* __restrict__ VT, bf16_t* __restrict__ Ctx) {
    __shared__ __align__(16) bf16_t Ks[2][64 * 64];    // 16 KB
    __shared__ __align__(16) bf16_t Vs[2][64 * 64];    // 16 KB
    __shared__ __align__(16) bf16_t Pw[4][32 * 72];    // 18 KB, per-wave [q][key]

    const int t = threadIdx.x, l = t & 63, w = t >> 6;   // w = 0..3
    const int lq = l & 31;          // this lane's q column
    const int hi = l >> 5;          // 0/1

    const int flat = blockIdx.x;
    const int xcd = flat & 7, j0 = flat >> 3;            // j0: 0..127
    const int qt  = NQT - 1 - (j0 >> 3);                 // heavy first
    const int rem = j0 & 7;
    const int combo = xcd * 2 + (rem >> 2);              // b*8+kvh
    const int b   = combo >> 3;
    const int kvh = combo & 7;
    const int h   = kvh * 4 + (rem & 3);

    const bf16_t* KB  = Kb + (size_t)b * S_LEN * KV_D + kvh * HEAD_D;
    const bf16_t* VTb = VT + ((size_t)(b * N_KVH + kvh) * HEAD_D) * S_LEN;

    const int q0w = qt * 128 + w * 32;
    const int qg  = q0w + lq;

    // Q fragments: B-operand, col=lane&31=q, k = (lane>>5)*8+i; 4 slabs of 16 d
    bf16x8 qf[4];
    {
        const bf16_t* qrow = Q + ((size_t)(b * S_LEN + qg)) * D_MODEL + h * HEAD_D;
#pragma unroll
        for (int s = 0; s < 4; s++)
            qf[s] = *(const bf16x8*)(qrow + s * 16 + hi * 8);
    }

    f32x16 oaccT[2];                 // O^T: col=q, row = d-frag (df*32 block)
    oaccT[0] = (f32x16)0.0f;
    oaccT[1] = (f32x16)0.0f;
    float lrow = 0.f;

    const int nkt = 2 * qt + 2;

    stage_K4(KB, Ks[0], 0, t);
    stage_V4(VTb, Vs[0], 0, t);
    __syncthreads();

    int cur = 0;
    for (int kt = 0; kt < nkt; ++kt) {
        const bool pre = (kt + 1 < nkt);
        if (pre) {
            stage_K4(KB, Ks[cur ^ 1], kt + 1, t);
            stage_V4(VTb, Vs[cur ^ 1], kt + 1, t);
        }

        if (kt * 64 <= q0w + 31) {                  // wave-uniform causal skip
            const bool diag = (kt * 64 + 63 > q0w);

            // ---- S^T = mfma32(K, Q): 8 mfma, kf = A (row=key, k=d-slab) ----
            f32x16 sfr[2];
            sfr[0] = (f32x16)0.0f;
            sfr[1] = (f32x16)0.0f;
            __builtin_amdgcn_s_setprio(1);
#pragma unroll
            for (int kh = 0; kh < 2; kh++)
#pragma unroll
                for (int s = 0; s < 4; s++) {
                    bf16x8 kf = *(const bf16x8*)&Ks[cur][(kh * 32 + lq) * 64 +
                                    ((s * 16 + hi * 8) ^ ((lq & 7) << 3))];
                    sfr[kh] = __builtin_amdgcn_mfma_f32_32x32x16_bf16(kf, qf[s],
                                                                      sfr[kh], 0, 0, 0);
                }
            __builtin_amdgcn_s_setprio(0);

            // ---- mask + exp2 + truncate-pack + in-register denominator ----
            float rs = 0.f;
#pragma unroll
            for (int kh = 0; kh < 2; kh++)
#pragma unroll
                for (int rq = 0; rq < 4; rq++) {
                    int keybase = kt * 64 + kh * 32 + rq * 8 + hi * 4;
                    float sc0 = sfr[kh][rq * 4 + 0];
                    float sc1 = sfr[kh][rq * 4 + 1];
                    float sc2 = sfr[kh][rq * 4 + 2];
                    float sc3 = sfr[kh][rq * 4 + 3];
                    if (diag) {
                        if (keybase + 0 > qg) sc0 = -1e30f;
                        if (keybase + 1 > qg) sc1 = -1e30f;
                        if (keybase + 2 > qg) sc2 = -1e30f;
                        if (keybase + 3 > qg) sc3 = -1e30f;
                    }
                    float e0 = exp2f(sc0), e1 = exp2f(sc1);
                    float e2 = exp2f(sc2), e3 = exp2f(sc3);
                    rs += (e0 + e1) + (e2 + e3);
                    unsigned u0 = __builtin_bit_cast(unsigned, e0);
                    unsigned u1 = __builtin_bit_cast(unsigned, e1);
                    unsigned u2 = __builtin_bit_cast(unsigned, e2);
                    unsigned u3 = __builtin_bit_cast(unsigned, e3);
                    uint2 pk;
                    pk.x = (u0 >> 16) | (u1 & 0xFFFF0000u);
                    pk.y = (u2 >> 16) | (u3 & 0xFFFF0000u);
                    *(uint2*)&Pw[w][lq * 72 + kh * 32 + rq * 8 + hi * 4] = pk;
                }
            lrow += rs;

            // ---- O^T += mfma32(V^T, P^T): 8 mfma ----
            __builtin_amdgcn_s_setprio(1);
#pragma unroll
            for (int kk = 0; kk < 4; kk++) {
                bf16x8 pf = *(const bf16x8*)&Pw[w][lq * 72 + kk * 16 + hi * 8];
#pragma unroll
                for (int df = 0; df < 2; df++) {
                    bf16x8 vf = *(const bf16x8*)&Vs[cur][(df * 32 + lq) * 64 +
                                    ((kk * 16 + hi * 8) ^ ((lq & 7) << 3))];
                    oaccT[df] = __builtin_amdgcn_mfma_f32_32x32x16_bf16(vf, pf,
                                        oaccT[df], 0, 0, 0);
                }
            }
            __builtin_amdgcn_s_setprio(0);
        }

        __syncthreads();
        cur ^= 1;
    }

    // ---- normalize + write ctx: lane owns q = qg; d = (rq*8 + hi*4 + j) + df*32 ----
    {
        float lsum = lrow + __shfl_xor(lrow, 32);
        float inv = 1.0f / lsum;
        bf16_t* crow = Ctx + ((size_t)(b * S_LEN + qg)) * D_MODEL + h * HEAD_D;
#pragma unroll
        for (int df = 0; df < 2; df++)
#pragma unroll
            for (int rq = 0; rq < 4; rq++) {
                bf16x4s ov;
                ov.x = __float2bfloat16(oaccT[df][rq * 4 + 0] * inv);
                ov.y = __float2bfloat16(oaccT[df][rq * 4 + 1] * inv);
                ov.z = __float2bfloat16(oaccT[df][rq * 4 + 2] * inv);
                ov.w = __float2bfloat16(oaccT[df][rq * 4 + 3] * inv);
                *(bf16x4s*)(crow + df * 32 + rq * 8 + hi * 4) = ov;
            }
    }
}

extern "C" void kernel_launch(void* const* d_in, const int* in_sizes, int n_in,
                              void* d_out, int out_size, void* d_ws, size_t ws_size,
                              hipStream_t stream) {
    const float* query = (const float*)d_in[0];
    const float* key_  = (const float*)d_in[1];
    const float* value = (const float*)d_in[2];
    const float* w_q = (const float*)d_in[3];
    const float* b_q = (const float*)d_in[4];
    const float* w_k = (const float*)d_in[5];
    const float* b_k = (const float*)d_in[6];
    const float* w_v = (const float*)d_in[7];
    const float* b_v = (const float*)d_in[8];
    const float* w_o = (const float*)d_in[9];
    const float* b_o = (const float*)d_in[10];
    float* out = (float*)d_out;

    char* ws = (char*)d_ws;
    bf16_t* qbf  = (bf16_t*)(ws);                       // 16MB (query bf16; reused as ctx)
    bf16_t* qb   = (bf16_t*)(ws + (size_t)(16 << 20));  // 16MB
    bf16_t* kb   = (bf16_t*)(ws + (size_t)(32 << 20));  // 4MB
    bf16_t* vt   = (bf16_t*)(ws + (size_t)(36 << 20));  // 4MB (transposed V)
    bf16_t* wtq  = (bf16_t*)(ws + (size_t)(40 << 20));  // 8MB
    bf16_t* wtk  = (bf16_t*)(ws + (size_t)(48 << 20));  // 2MB
    bf16_t* wtv  = (bf16_t*)(ws + (size_t)(50 << 20));  // 2MB
    bf16_t* wto  = (bf16_t*)(ws + (size_t)(52 << 20));  // 8MB
    float* cosT  = (float*)(ws + (size_t)(60 << 20));   // 256KB
    float* sinT  = (float*)(ws + (size_t)(60 << 20) + (256 << 10));
    bf16_t* kbf  = (bf16_t*)(ws + (size_t)(61 << 20));  // 16MB (key bf16)
    bf16_t* vbf  = (bf16_t*)(ws + (size_t)(77 << 20));  // 16MB (value bf16)

    // 1) weight transposes + RoPE table + q/k/v conversion
    prep_kernel<<<11840, 256, 0, stream>>>(w_q, w_k, w_v, w_o, wtq, wtk, wtv, wto,
                                           query, key_, value, qbf, kbf, vbf, cosT, sinT);

    // 2) fused Q+K+V projection GEMM
    gqa_qkv_kernel<<<768, 256, 0, stream>>>(qbf, kbf, vbf, wtq, wtk, wtv,
                                            b_q, b_k, b_v, qb, kb, vt, cosT, sinT);

    // 3) attention -> ctx (reuses qbf); 32x32 MFMA, 4-wave blocks
    gqa_attn_kernel<<<1024, 256, 0, stream>>>(qb, kb, vt, qbf);

    // 4) output projection -> fp32 d_out
    gqa_gemm_kernel<0, 1, 0><<<512, 256, 0, stream>>>(
        qbf, wto, b_o, out, M_ROWS, D_MODEL, D_MODEL, cosT, sinT);
}